// Round 20
// baseline (202.591 us; speedup 1.0000x reference)
//
// v15 — triangle-only self slots: GEMM kinds 2/3 write lower-triangle tiles only;
// self sweep = fused row+col triangle sweep (LDS/global atomicMin keys, 3-buffer,
// 1 barrier/iter, redundant apply => local freeze). OT path unchanged from v14.
#include <hip/hip_runtime.h>
#include <hip/hip_fp16.h>

#define NP 1500
#define DD 300
#define DP 320
#define VSZ 1536
#define NB 4
#define TILE 16384
#define TSZ (1536*1536)
#define OTB 8               // blocks per OT group
#define SELFB 8             // blocks per self group
#define KADD 1.8283051e-8f
#define PADVAL (-60000.0f)
#define SCALE 256.0f
#define SCALE2INV (1.0f/65536.0f)
#define FTHR 1e-8f

typedef _Float16 f16x8 __attribute__((ext_vector_type(8)));
typedef float f32x4 __attribute__((ext_vector_type(4)));
typedef unsigned int u32x4 __attribute__((ext_vector_type(4)));

__device__ __forceinline__ unsigned fkey(float f){
    unsigned b = __float_as_uint(f);
    return (b & 0x80000000u) ? ~b : (b | 0x80000000u);
}
__device__ __forceinline__ float funkey(unsigned k){
    unsigned b = (k & 0x80000000u) ? (k & 0x7FFFFFFFu) : ~k;
    return __uint_as_float(b);
}

__global__ void k_zero(float* p, int n){
    int i = blockIdx.x*blockDim.x + threadIdx.x;
    if (i < n) p[i] = 0.f;
}
__global__ void k_initu(unsigned* p, int n){
    int i = blockIdx.x*blockDim.x + threadIdx.x;
    if (i < n) p[i] = 0xFFFFFFFFu;
}

// ---- deterministic column sums ----
__global__ __launch_bounds__(256) void k_colsum_p1(const float* __restrict__ x, const float* __restrict__ y,
                                                   float* __restrict__ partial){
    int rc = blockIdx.x, b = blockIdx.y, src = blockIdx.z;
    const float* in = (src ? y : x) + ((size_t)b*NP + rc*125)*DD;
    int tid = threadIdx.x;
    float s0 = 0.f, s1 = 0.f;
    #pragma unroll 4
    for (int r = 0; r < 125; ++r){
        float v0 = in[r*DD + tid];
        s0 = fmaf(v0, v0, s0);
        if (tid < 44){
            float v1 = in[r*DD + 256 + tid];
            s1 = fmaf(v1, v1, s1);
        }
    }
    float* po = partial + (((size_t)rc*NB + b)*2 + src)*DD;
    po[tid] = s0;
    if (tid < 44) po[256 + tid] = s1;
}

__global__ void k_colsum_p2(const float* __restrict__ partial,
                            float* __restrict__ csx, float* __restrict__ csy){
    int idx = blockIdx.x*256 + threadIdx.x;
    if (idx >= NB*2*DD) return;
    int c = idx % DD; int t = idx / DD; int src = t & 1; int b = t >> 1;
    float s = 0.f;
    #pragma unroll
    for (int rc = 0; rc < 12; ++rc)
        s += partial[(((size_t)rc*NB + b)*2 + src)*DD + c];
    (src ? csy : csx)[b*DD + c] = s;
}

// ---- normalize + row-norm init; side1 seeds OT cmin buffer 2 with fkey(-(ynrm+KADD)) ----
__global__ __launch_bounds__(256) void k_normrow(const float* __restrict__ x, const float* __restrict__ y,
        const float* __restrict__ csx, const float* __restrict__ csy,
        __half* __restrict__ pxh, __half* __restrict__ pyh,
        float* __restrict__ psxx0, float* __restrict__ uvv, float* __restrict__ psyy0,
        unsigned* __restrict__ cmin){
    int gw = ((int)blockIdx.x*256 + threadIdx.x) >> 6;
    int lane = threadIdx.x & 63;
    int src = (gw >= NB*NP) ? 1 : 0;
    int rem = gw - src*NB*NP;
    int b = rem / NP, i = rem - b*NP;
    const float* in = (src ? y : x) + ((size_t)b*NP + i)*DD;
    const float* cs = (src ? csy : csx) + b*DD;
    __half* oph = (src ? pyh : pxh) + ((size_t)b*NP + i)*DP;
    float s = 0.f;
    #pragma unroll
    for (int it = 0; it < 5; ++it){
        int c = lane + it*64;
        float vu = 0.f, hv = 0.f;
        if (c < DD){
            float u = in[c];
            vu = u*u / cs[c];
            hv = vu * SCALE;
        }
        oph[c] = __float2half(hv);
        s = fmaf(vu, vu, s);
    }
    #pragma unroll
    for (int o2 = 1; o2 < 64; o2 <<= 1) s += __shfl_xor(s, o2, 64);
    if (lane == 0){
        float val = 0.5f * s;
        int o = b*VSZ + i;
        if (src){
            uvv[o] = val; psyy0[o] = val;
            cmin[(b*3 + 2)*1536 + i] = fkey(-(val + KADD));
        } else {
            psxx0[o] = val;
        }
    }
}

// ---- MFMA GEMM: BK=64, prefetch, swizzled LDS, nontemporal stores.
// kinds {0,2,3}; kind0 full grid, kinds 2/3 lower-triangle tiles ONLY (no transpose write).
__global__ __launch_bounds__(256) void k_gemm_mfma(const __half* __restrict__ pxh,
                                                   const __half* __restrict__ pyh,
                                                   __half* __restrict__ P){
    int z = blockIdx.z; int b = z/3; int kidx = z - b*3;
    int kind = (kidx==0) ? 0 : ((kidx==1) ? 2 : 3);
    int bx = blockIdx.x, by = blockIdx.y;
    if (kind != 0 && by > bx) return;
    const __half* A = (((kind==0)||(kind==2)) ? pxh : pyh) + (size_t)b*NP*DP;
    const __half* B = (((kind==0)||(kind==3)) ? pyh : pxh) + (size_t)b*NP*DP;

    __shared__ __align__(16) char smem[128*136*2];
    char* ldsA = smem;
    char* ldsB = smem + 16384;
    __half* ldsO = (__half*)smem;

    int tid = threadIdx.x;
    int row0 = bx*128, col0 = by*128;
    int lane = tid & 63;
    int w = tid >> 6;
    int wm = (w >> 1)*64, wn = (w & 1)*64;
    int g8 = tid & 7, rw = tid >> 3;
    int lr = lane & 15, cq = lane >> 4;

    f32x4 acc[4][4];
    #pragma unroll
    for (int mi = 0; mi < 4; ++mi)
        #pragma unroll
        for (int ni = 0; ni < 4; ++ni)
            acc[mi][ni] = (f32x4){0.f, 0.f, 0.f, 0.f};

    uint4 va[4], vb[4];
    #pragma unroll
    for (int is = 0; is < 4; ++is){
        int r = rw + is*32;
        int ar = row0 + r; if (ar > NP-1) ar = NP-1;
        int br = col0 + r; if (br > NP-1) br = NP-1;
        va[is] = *(const uint4*)(A + (size_t)ar*DP + g8*8);
        vb[is] = *(const uint4*)(B + (size_t)br*DP + g8*8);
    }
    #pragma unroll
    for (int ks = 0; ks < 5; ++ks){
        if (ks) __syncthreads();
        #pragma unroll
        for (int is = 0; is < 4; ++is){
            int r = rw + is*32;
            int pc = g8 ^ (r & 7);
            *(uint4*)(ldsA + r*128 + pc*16) = va[is];
            *(uint4*)(ldsB + r*128 + pc*16) = vb[is];
        }
        __syncthreads();
        if (ks < 4){
            int k0 = (ks + 1)*64;
            #pragma unroll
            for (int is = 0; is < 4; ++is){
                int r = rw + is*32;
                int ar = row0 + r; if (ar > NP-1) ar = NP-1;
                int br = col0 + r; if (br > NP-1) br = NP-1;
                va[is] = *(const uint4*)(A + (size_t)ar*DP + k0 + g8*8);
                vb[is] = *(const uint4*)(B + (size_t)br*DP + k0 + g8*8);
            }
        }
        f16x8 av[2][4], bv[2][4];
        #pragma unroll
        for (int ksl = 0; ksl < 2; ++ksl){
            int lc = ksl*4 + cq;
            int pc = (lc ^ (lr & 7))*16;
            #pragma unroll
            for (int mi = 0; mi < 4; ++mi)
                av[ksl][mi] = *(const f16x8*)(ldsA + (wm + mi*16 + lr)*128 + pc);
            #pragma unroll
            for (int ni = 0; ni < 4; ++ni)
                bv[ksl][ni] = *(const f16x8*)(ldsB + (wn + ni*16 + lr)*128 + pc);
        }
        #pragma unroll
        for (int ksl = 0; ksl < 2; ++ksl)
            #pragma unroll
            for (int mi = 0; mi < 4; ++mi)
                #pragma unroll
                for (int ni = 0; ni < 4; ++ni)
                    acc[mi][ni] = __builtin_amdgcn_mfma_f32_16x16x32_f16(av[ksl][mi], bv[ksl][ni], acc[mi][ni], 0, 0, 0);
    }

    int cqe = lane >> 4;
    __syncthreads();
    #pragma unroll
    for (int mi = 0; mi < 4; ++mi)
        #pragma unroll
        for (int ni = 0; ni < 4; ++ni){
            int lcol = wn + ni*16 + lr;
            bool colok = (col0 + lcol) < NP;
            #pragma unroll
            for (int v = 0; v < 4; ++v){
                int lrow = wm + mi*16 + cqe*4 + v;
                bool rowok = (row0 + lrow) < NP;
                ldsO[lrow*136 + lcol] = __float2half((colok && rowok) ? acc[mi][ni][v]*SCALE2INV : PADVAL);
            }
        }
    __syncthreads();
    {
        __half* tileD = P + (size_t)(b*4 + kind)*TSZ + ((size_t)bx*12 + by)*TILE;
        #pragma unroll
        for (int it = 0; it < 8; ++it){
            int e = it*256 + tid;
            int r = e >> 4, q = e & 15;
            u32x4 vv = *(const u32x4*)(ldsO + r*136 + q*8);
            __builtin_nontemporal_store(vv, (u32x4*)(tileD + r*128 + q*8));
        }
    }
}

// ---- persistent Sinkhorn ----
__device__ __forceinline__ void groupbar(int* slot, int gsz){
    __syncthreads();
    if (threadIdx.x == 0){
        __hip_atomic_fetch_add(slot, 1, __ATOMIC_RELEASE, __HIP_MEMORY_SCOPE_AGENT);
        while (__hip_atomic_load(slot, __ATOMIC_ACQUIRE, __HIP_MEMORY_SCOPE_AGENT) < gsz)
            __builtin_amdgcn_s_sleep(1);
    }
    __syncthreads();
}

#define ROWPTR(PK, i) ((PK) + (size_t)((i) >> 7)*12*TILE + (size_t)((i) & 127)*128)

__global__ __launch_bounds__(1024, 1) void k_sink(const __half* __restrict__ P,
        float* __restrict__ fs, float* __restrict__ uvv,
        float* __restrict__ px0, float* __restrict__ px1,
        float* __restrict__ py0, float* __restrict__ py1,
        int* __restrict__ bars, int* __restrict__ flags,
        unsigned* __restrict__ cmin){
    int tid = threadIdx.x;
    int lane = tid & 63;
    int wid = tid >> 6;
    int blk = (int)blockIdx.x;
    __shared__ int s_ch;
    __shared__ unsigned lmin[1536];

    if (blk < 4*OTB){
        // ---------- OT group (fused colmin), unchanged from v14 ----------
        int b = blk / OTB, lb = blk - b*OTB;
        int gw = lb*16 + wid;
        const int NWV = OTB*16;     // 128 waves
        int* gbarp  = bars + b*64;
        int* gflagp = flags + b*64;
        const __half* P0 = P + (size_t)(b*4 + 0)*TSZ;
        float* fsb = fs + b*VSZ;
        float* uvb = uvv + b*VSZ;
        unsigned* cm = cmin + b*3*1536;

        int colb[3];
        #pragma unroll
        for (int it = 0; it < 3; ++it){
            int c = lane + it*64;
            colb[it] = ((c >> 4) << 7) + ((c & 15) << 3);
        }

        int lastT = 0;
        for (int t = 0; t < 30; ++t){
            unsigned* rdbuf = cm + ((t + 2) % 3)*1536;
            unsigned* wrbuf = cm + (t % 3)*1536;
            unsigned* rsbuf = cm + ((t + 1) % 3)*1536;
            if (tid == 0) s_ch = 0;
            for (int idx = tid; idx < 1536; idx += 1024) lmin[idx] = 0xFFFFFFFFu;
            float Au[3][8];
            #pragma unroll
            for (int it = 0; it < 3; ++it){
                uint4 k0 = *(const uint4*)(rdbuf + colb[it]);
                uint4 k1 = *(const uint4*)(rdbuf + colb[it] + 4);
                unsigned kk[8] = {k0.x, k0.y, k0.z, k0.w, k1.x, k1.y, k1.z, k1.w};
                #pragma unroll
                for (int e = 0; e < 8; ++e){
                    int col = colb[it] + e;
                    Au[it][e] = (col < NP) ? (-(funkey(kk[e]) + KADD)) : 3.0e38f;
                }
            }
            __syncthreads();
            float amin[3][8];
            #pragma unroll
            for (int it = 0; it < 3; ++it)
                #pragma unroll
                for (int e = 0; e < 8; ++e) amin[it][e] = 3.0e38f;
            int ch = 0;
            for (int i = gw; i < NP; i += NWV){
                const __half* rowb = ROWPTR(P0, i);
                uint4 pk[3];
                #pragma unroll
                for (int it = 0; it < 3; ++it){
                    int c = lane + it*64, tt = c >> 4, q = c & 15;
                    pk[it] = *(const uint4*)(rowb + (size_t)tt*TILE + q*8);
                }
                float cf[3][8];
                float m = 3.0e38f;
                #pragma unroll
                for (int it = 0; it < 3; ++it){
                    float2 c0 = __half22float2(*(const __half2*)&pk[it].x);
                    float2 c1 = __half22float2(*(const __half2*)&pk[it].y);
                    float2 c2 = __half22float2(*(const __half2*)&pk[it].z);
                    float2 c3 = __half22float2(*(const __half2*)&pk[it].w);
                    cf[it][0] = c0.x; cf[it][1] = c0.y; cf[it][2] = c1.x; cf[it][3] = c1.y;
                    cf[it][4] = c2.x; cf[it][5] = c2.y; cf[it][6] = c3.x; cf[it][7] = c3.y;
                    #pragma unroll
                    for (int e = 0; e < 8; ++e) m = fminf(m, Au[it][e] - cf[it][e]);
                }
                #pragma unroll
                for (int o = 1; o < 64; o <<= 1) m = fminf(m, __shfl_xor(m, o, 64));
                float nv = -(m + KADD);
                if (lane == 0){
                    if (fabsf(nv - fsb[i]) > FTHR) ch = 1;
                    fsb[i] = nv;
                }
                #pragma unroll
                for (int it = 0; it < 3; ++it)
                    #pragma unroll
                    for (int e = 0; e < 8; ++e)
                        amin[it][e] = fminf(amin[it][e], nv - cf[it][e]);
            }
            if (ch) s_ch = 1;
            #pragma unroll
            for (int it = 0; it < 3; ++it)
                #pragma unroll
                for (int e = 0; e < 8; ++e)
                    atomicMin(&lmin[colb[it] + e], fkey(amin[it][e]));
            __syncthreads();
            for (int idx = tid; idx < 1536; idx += 1024)
                atomicMin(&wrbuf[idx], lmin[idx]);
            if (tid < 192) rsbuf[lb*192 + tid] = 0xFFFFFFFFu;
            if (tid == 0 && s_ch) atomicOr(&gflagp[t], 1);
            groupbar(&gbarp[t], OTB);
            lastT = t;
            int fA = __hip_atomic_load(&gflagp[t], __ATOMIC_RELAXED, __HIP_MEMORY_SCOPE_AGENT);
            if (fA == 0) break;
        }
        unsigned* fin = cm + (lastT % 3)*1536;
        for (int j = tid; j < NP; j += 1024)
            uvb[j] = -(funkey(fin[j]) + KADD);
    } else {
        // ---------- self groups: fused triangle sweep ----------
        int sg = blk - 4*OTB;
        int g = sg / SELFB, lb = sg - g*SELFB;
        int gwave = lb*16 + wid;            // 0..127
        int b = g >> 1, kind = 2 + (g & 1);
        float* bufA = ((g & 1) ? py0 : px0) + b*VSZ;
        float* bufB = ((g & 1) ? py1 : px1) + b*VSZ;
        int* gbarp  = bars + (4 + g)*64;
        unsigned* cm = cmin + (4 + g)*3*1536;
        const __half* PK = P + (size_t)(b*4 + kind)*TSZ;
        int g4 = lane >> 4, lc = (lane & 15) << 3;
        for (int t = 0; t < 30; ++t){
            unsigned* wrbuf = cm + (t % 3)*1536;
            unsigned* rsbuf = cm + ((t + 1) % 3)*1536;
            if (tid == 0) s_ch = 0;
            for (int idx = tid; idx < 1536; idx += 1024) lmin[idx] = 0xFFFFFFFFu;
            __syncthreads();
            // triangle sweep: element (i,j), j-tile <= i-tile; contributions to i (row) and j (col)
            for (int i = gwave; i < NP; i += 128){
                int bxi = i >> 7;
                const __half* rowbase = PK + ((size_t)bxi*12)*TILE + (size_t)(i & 127)*128;
                float psi = bufA[i];
                float rowm = 3.0e38f;
                for (int tb = 0; tb <= bxi; tb += 4){
                    int by = tb + g4;
                    if (by <= bxi){
                        uint4 pk = *(const uint4*)(rowbase + (size_t)by*TILE + lc);
                        int j0 = (by << 7) + lc;
                        float4 p0 = *(const float4*)(bufA + j0);
                        float4 p1 = *(const float4*)(bufA + j0 + 4);
                        float2 c0 = __half22float2(*(const __half2*)&pk.x);
                        float2 c1 = __half22float2(*(const __half2*)&pk.y);
                        float2 c2 = __half22float2(*(const __half2*)&pk.z);
                        float2 c3 = __half22float2(*(const __half2*)&pk.w);
                        float cf[8] = {c0.x, c0.y, c1.x, c1.y, c2.x, c2.y, c3.x, c3.y};
                        float pj[8] = {p0.x, p0.y, p0.z, p0.w, p1.x, p1.y, p1.z, p1.w};
                        #pragma unroll
                        for (int e = 0; e < 8; ++e) rowm = fminf(rowm, pj[e] - cf[e]);
                        #pragma unroll
                        for (int e = 0; e < 8; ++e)
                            atomicMin(&lmin[j0 + e], fkey(psi - cf[e]));
                    }
                }
                #pragma unroll
                for (int o = 1; o < 64; o <<= 1) rowm = fminf(rowm, __shfl_xor(rowm, o, 64));
                if (lane == 0) atomicMin(&lmin[i], fkey(rowm));
            }
            __syncthreads();
            for (int idx = tid; idx < 1536; idx += 1024)
                atomicMin(&wrbuf[idx], lmin[idx]);
            if (tid < 192) rsbuf[lb*192 + tid] = 0xFFFFFFFFu;
            groupbar(&gbarp[t], SELFB);
            // apply (all indexes redundantly -> identical freeze decision per block)
            int ch = 0;
            for (int idx = tid; idx < NP; idx += 1024){
                float m = funkey(wrbuf[idx]);
                float ov = bufA[idx];
                float nv = 0.5f*(ov - m - KADD);
                if (fabsf(nv - ov) > FTHR) ch = 1;
                bufB[idx] = nv;
            }
            if (ch) s_ch = 1;
            __syncthreads();
            if (s_ch == 0) break;   // frozen: bufA == bufB within FTHR
            { float* tmp = bufA; bufA = bufB; bufB = tmp; }
        }
        // 30 full iters: t=29 apply writes px0/py0; frozen-break leaves both equal within FTHR.
    }
}

// S = (4/1500) * sum_b,i (psxx + psyy - fs - u)
__global__ void k_final(const float* __restrict__ fs, const float* __restrict__ u,
                        const float* __restrict__ psxx, const float* __restrict__ psyy,
                        float* __restrict__ out){
    __shared__ double red[256];
    double s = 0.0;
    for (int t = threadIdx.x; t < NB*NP; t += 256){
        int b = t / NP, i = t - b*NP; int o = b*VSZ + i;
        s += (double)psxx[o] + (double)psyy[o] - (double)fs[o] - (double)u[o];
    }
    red[threadIdx.x] = s; __syncthreads();
    for (int w = 128; w > 0; w >>= 1){
        if (threadIdx.x < w) red[threadIdx.x] += red[threadIdx.x + w];
        __syncthreads();
    }
    if (threadIdx.x == 0) out[0] = (float)(red[0] * (4.0/1500.0));
}

extern "C" void kernel_launch(void* const* d_in, const int* in_sizes, int n_in,
                              void* d_out, int out_size, void* d_ws, size_t ws_size,
                              hipStream_t stream) {
    const float* x = (const float*)d_in[0];
    const float* y = (const float*)d_in[1];
    float* out = (float*)d_out;

    __half* pxh = (__half*)d_ws;
    __half* pyh = pxh + (size_t)NB*NP*DP;
    float* csx = (float*)(pyh + (size_t)NB*NP*DP);
    float* csy = csx + NB*DD;
    float* fs  = csy + NB*DD;
    float* uv  = fs + NB*VSZ;
    float* px0 = uv + NB*VSZ;
    float* px1 = px0 + NB*VSZ;
    float* py0 = px1 + NB*VSZ;
    float* py1 = py0 + NB*VSZ;
    int* bars  = (int*)(py1 + NB*VSZ);                 // 12*64 ints
    int* flags = bars + 12*64;                         // 12*64 ints
    unsigned* cmin = (unsigned*)(flags + 12*64);       // 12 groups * 3 * 1536 uints
    float* partial = (float*)(cmin + 12*3*1536);       // 12*NB*2*DD floats
    float* smallEnd = partial + (size_t)12*NB*2*DD;
    size_t pOff = (((size_t)((char*)smallEnd - (char*)d_ws)) + 255) & ~(size_t)255;
    __half* P = (__half*)((char*)d_ws + pOff);

    int nzero = (int)(((float*)(flags + 12*64)) - csx);
    k_zero<<<(nzero + 255)/256, 256, 0, stream>>>(csx, nzero);
    k_initu<<<(12*3*1536 + 255)/256, 256, 0, stream>>>(cmin, 12*3*1536);

    k_colsum_p1<<<dim3(12, NB, 2), 256, 0, stream>>>(x, y, partial);
    k_colsum_p2<<<10, 256, 0, stream>>>(partial, csx, csy);

    k_normrow<<<3000, 256, 0, stream>>>(x, y, csx, csy, pxh, pyh, px0, uv, py0, cmin);

    k_gemm_mfma<<<dim3(12, 12, 12), 256, 0, stream>>>(pxh, pyh, P);

    k_sink<<<4*OTB + 8*SELFB, 1024, 0, stream>>>(P, fs, uv, px0, px1, py0, py1, bars, flags, cmin);

    k_final<<<1, 256, 0, stream>>>(fs, uv, px0, py0, out);
}

// Round 21
// 187.105 us; speedup vs baseline: 1.0828x; 1.0828x over previous
//
// v16 — v14 with nontemporal stores removed from GEMM (P lands in L2/L3; NT was
// forcing ~3.8x-amplified HBM write traffic + HBM re-reads in k_sink) and
// k_zero/k_initu merged. Everything else identical to v14 (best: 193.4 us).
#include <hip/hip_runtime.h>
#include <hip/hip_fp16.h>

#define NP 1500
#define DD 300
#define DP 320
#define VSZ 1536
#define NB 4
#define TILE 16384
#define TSZ (1536*1536)
#define OTB 8               // blocks per OT group
#define SELFB 8             // blocks per self group
#define KADD 1.8283051e-8f
#define PADVAL (-60000.0f)
#define SCALE 256.0f
#define SCALE2INV (1.0f/65536.0f)
#define FTHR 1e-8f

typedef _Float16 f16x8 __attribute__((ext_vector_type(8)));
typedef float f32x4 __attribute__((ext_vector_type(4)));

__device__ __forceinline__ unsigned fkey(float f){
    unsigned b = __float_as_uint(f);
    return (b & 0x80000000u) ? ~b : (b | 0x80000000u);
}
__device__ __forceinline__ float funkey(unsigned k){
    unsigned b = (k & 0x80000000u) ? (k & 0x7FFFFFFFu) : ~k;
    return __uint_as_float(b);
}

// zero nz floats then set nk uints to 0xFFFFFFFF (one launch)
__global__ void k_init(float* pz, int nz, unsigned* pk, int nk){
    int i = blockIdx.x*blockDim.x + threadIdx.x;
    if (i < nz) pz[i] = 0.f;
    int j = i - nz;
    if (j >= 0 && j < nk) pk[j] = 0xFFFFFFFFu;
}

// ---- deterministic column sums ----
__global__ __launch_bounds__(256) void k_colsum_p1(const float* __restrict__ x, const float* __restrict__ y,
                                                   float* __restrict__ partial){
    int rc = blockIdx.x, b = blockIdx.y, src = blockIdx.z;
    const float* in = (src ? y : x) + ((size_t)b*NP + rc*125)*DD;
    int tid = threadIdx.x;
    float s0 = 0.f, s1 = 0.f;
    #pragma unroll 4
    for (int r = 0; r < 125; ++r){
        float v0 = in[r*DD + tid];
        s0 = fmaf(v0, v0, s0);
        if (tid < 44){
            float v1 = in[r*DD + 256 + tid];
            s1 = fmaf(v1, v1, s1);
        }
    }
    float* po = partial + (((size_t)rc*NB + b)*2 + src)*DD;
    po[tid] = s0;
    if (tid < 44) po[256 + tid] = s1;
}

__global__ void k_colsum_p2(const float* __restrict__ partial,
                            float* __restrict__ csx, float* __restrict__ csy){
    int idx = blockIdx.x*256 + threadIdx.x;
    if (idx >= NB*2*DD) return;
    int c = idx % DD; int t = idx / DD; int src = t & 1; int b = t >> 1;
    float s = 0.f;
    #pragma unroll
    for (int rc = 0; rc < 12; ++rc)
        s += partial[(((size_t)rc*NB + b)*2 + src)*DD + c];
    (src ? csy : csx)[b*DD + c] = s;
}

// ---- normalize + row-norm init; side1 seeds OT cmin buffer 2 with fkey(-(ynrm+KADD)) ----
__global__ __launch_bounds__(256) void k_normrow(const float* __restrict__ x, const float* __restrict__ y,
        const float* __restrict__ csx, const float* __restrict__ csy,
        __half* __restrict__ pxh, __half* __restrict__ pyh,
        float* __restrict__ psxx0, float* __restrict__ uvv, float* __restrict__ psyy0,
        unsigned* __restrict__ cmin){
    int gw = ((int)blockIdx.x*256 + threadIdx.x) >> 6;
    int lane = threadIdx.x & 63;
    int src = (gw >= NB*NP) ? 1 : 0;
    int rem = gw - src*NB*NP;
    int b = rem / NP, i = rem - b*NP;
    const float* in = (src ? y : x) + ((size_t)b*NP + i)*DD;
    const float* cs = (src ? csy : csx) + b*DD;
    __half* oph = (src ? pyh : pxh) + ((size_t)b*NP + i)*DP;
    float s = 0.f;
    #pragma unroll
    for (int it = 0; it < 5; ++it){
        int c = lane + it*64;
        float vu = 0.f, hv = 0.f;
        if (c < DD){
            float u = in[c];
            vu = u*u / cs[c];
            hv = vu * SCALE;
        }
        oph[c] = __float2half(hv);
        s = fmaf(vu, vu, s);
    }
    #pragma unroll
    for (int o2 = 1; o2 < 64; o2 <<= 1) s += __shfl_xor(s, o2, 64);
    if (lane == 0){
        float val = 0.5f * s;
        int o = b*VSZ + i;
        if (src){
            uvv[o] = val; psyy0[o] = val;
            cmin[(b*3 + 2)*1536 + i] = fkey(-(val + KADD));
        } else {
            psxx0[o] = val;
        }
    }
}

// ---- MFMA GEMM: BK=64, prefetch, swizzled LDS, PLAIN stores (P stays cache-resident).
// kinds {0,2,3}; kind0 direct tile only; kinds 2/3 triangle compute + direct & transposed write.
__global__ __launch_bounds__(256) void k_gemm_mfma(const __half* __restrict__ pxh,
                                                   const __half* __restrict__ pyh,
                                                   __half* __restrict__ P){
    int z = blockIdx.z; int b = z/3; int kidx = z - b*3;
    int kind = (kidx==0) ? 0 : ((kidx==1) ? 2 : 3);
    int bx = blockIdx.x, by = blockIdx.y;
    if (kind != 0 && by > bx) return;
    const __half* A = (((kind==0)||(kind==2)) ? pxh : pyh) + (size_t)b*NP*DP;
    const __half* B = (((kind==0)||(kind==3)) ? pyh : pxh) + (size_t)b*NP*DP;

    __shared__ __align__(16) char smem[128*136*2];
    char* ldsA = smem;
    char* ldsB = smem + 16384;
    __half* ldsO = (__half*)smem;

    int tid = threadIdx.x;
    int row0 = bx*128, col0 = by*128;
    int lane = tid & 63;
    int w = tid >> 6;
    int wm = (w >> 1)*64, wn = (w & 1)*64;
    int g8 = tid & 7, rw = tid >> 3;
    int lr = lane & 15, cq = lane >> 4;

    f32x4 acc[4][4];
    #pragma unroll
    for (int mi = 0; mi < 4; ++mi)
        #pragma unroll
        for (int ni = 0; ni < 4; ++ni)
            acc[mi][ni] = (f32x4){0.f, 0.f, 0.f, 0.f};

    uint4 va[4], vb[4];
    #pragma unroll
    for (int is = 0; is < 4; ++is){
        int r = rw + is*32;
        int ar = row0 + r; if (ar > NP-1) ar = NP-1;
        int br = col0 + r; if (br > NP-1) br = NP-1;
        va[is] = *(const uint4*)(A + (size_t)ar*DP + g8*8);
        vb[is] = *(const uint4*)(B + (size_t)br*DP + g8*8);
    }
    #pragma unroll
    for (int ks = 0; ks < 5; ++ks){
        if (ks) __syncthreads();
        #pragma unroll
        for (int is = 0; is < 4; ++is){
            int r = rw + is*32;
            int pc = g8 ^ (r & 7);
            *(uint4*)(ldsA + r*128 + pc*16) = va[is];
            *(uint4*)(ldsB + r*128 + pc*16) = vb[is];
        }
        __syncthreads();
        if (ks < 4){
            int k0 = (ks + 1)*64;
            #pragma unroll
            for (int is = 0; is < 4; ++is){
                int r = rw + is*32;
                int ar = row0 + r; if (ar > NP-1) ar = NP-1;
                int br = col0 + r; if (br > NP-1) br = NP-1;
                va[is] = *(const uint4*)(A + (size_t)ar*DP + k0 + g8*8);
                vb[is] = *(const uint4*)(B + (size_t)br*DP + k0 + g8*8);
            }
        }
        f16x8 av[2][4], bv[2][4];
        #pragma unroll
        for (int ksl = 0; ksl < 2; ++ksl){
            int lc = ksl*4 + cq;
            int pc = (lc ^ (lr & 7))*16;
            #pragma unroll
            for (int mi = 0; mi < 4; ++mi)
                av[ksl][mi] = *(const f16x8*)(ldsA + (wm + mi*16 + lr)*128 + pc);
            #pragma unroll
            for (int ni = 0; ni < 4; ++ni)
                bv[ksl][ni] = *(const f16x8*)(ldsB + (wn + ni*16 + lr)*128 + pc);
        }
        #pragma unroll
        for (int ksl = 0; ksl < 2; ++ksl)
            #pragma unroll
            for (int mi = 0; mi < 4; ++mi)
                #pragma unroll
                for (int ni = 0; ni < 4; ++ni)
                    acc[mi][ni] = __builtin_amdgcn_mfma_f32_16x16x32_f16(av[ksl][mi], bv[ksl][ni], acc[mi][ni], 0, 0, 0);
    }

    int cqe = lane >> 4;
    __syncthreads();
    #pragma unroll
    for (int mi = 0; mi < 4; ++mi)
        #pragma unroll
        for (int ni = 0; ni < 4; ++ni){
            int lcol = wn + ni*16 + lr;
            bool colok = (col0 + lcol) < NP;
            #pragma unroll
            for (int v = 0; v < 4; ++v){
                int lrow = wm + mi*16 + cqe*4 + v;
                bool rowok = (row0 + lrow) < NP;
                ldsO[lrow*136 + lcol] = __float2half((colok && rowok) ? acc[mi][ni][v]*SCALE2INV : PADVAL);
            }
        }
    __syncthreads();
    {
        __half* tileD = P + (size_t)(b*4 + kind)*TSZ + ((size_t)bx*12 + by)*TILE;
        #pragma unroll
        for (int it = 0; it < 8; ++it){
            int e = it*256 + tid;
            int r = e >> 4, q = e & 15;
            *(uint4*)(tileD + r*128 + q*8) = *(const uint4*)(ldsO + r*136 + q*8);
        }
    }
    if (kind != 0 && bx != by){
        __syncthreads();
        #pragma unroll
        for (int mi = 0; mi < 4; ++mi)
            #pragma unroll
            for (int ni = 0; ni < 4; ++ni){
                int trow = wn + ni*16 + lr;
                bool colok = (col0 + trow) < NP;
                #pragma unroll
                for (int v = 0; v < 4; ++v){
                    int tcol = wm + mi*16 + cqe*4 + v;
                    bool rowok = (row0 + tcol) < NP;
                    ldsO[trow*136 + tcol] = __float2half((rowok && colok) ? acc[mi][ni][v]*SCALE2INV : PADVAL);
                }
            }
        __syncthreads();
        __half* tileT = P + (size_t)(b*4 + kind)*TSZ + ((size_t)by*12 + bx)*TILE;
        #pragma unroll
        for (int it = 0; it < 8; ++it){
            int e = it*256 + tid;
            int r = e >> 4, q = e & 15;
            *(uint4*)(tileT + r*128 + q*8) = *(const uint4*)(ldsO + r*136 + q*8);
        }
    }
}

// ---- persistent Sinkhorn (v14): OT fused colmin; self full-row 2-deep ----
__device__ __forceinline__ void groupbar(int* slot, int gsz){
    __syncthreads();
    if (threadIdx.x == 0){
        __hip_atomic_fetch_add(slot, 1, __ATOMIC_RELEASE, __HIP_MEMORY_SCOPE_AGENT);
        while (__hip_atomic_load(slot, __ATOMIC_ACQUIRE, __HIP_MEMORY_SCOPE_AGENT) < gsz)
            __builtin_amdgcn_s_sleep(1);
    }
    __syncthreads();
}

__device__ __forceinline__ void loadvec(const float* __restrict__ v, float4* A0, float4* A1, int lane){
    const float4* a4 = (const float4*)v;
    #pragma unroll
    for (int it = 0; it < 3; ++it){
        int c = lane + it*64, tt = c >> 4, q = c & 15;
        A0[it] = a4[tt*32 + q*2];
        A1[it] = a4[tt*32 + q*2 + 1];
    }
}

__device__ __forceinline__ void loadrow(const __half* __restrict__ rowb, int lane, uint4* pk){
    #pragma unroll
    for (int it = 0; it < 3; ++it){
        int c = lane + it*64, tt = c >> 4, q = c & 15;
        pk[it] = *(const uint4*)(rowb + (size_t)tt*TILE + q*8);
    }
}

__device__ __forceinline__ float redrow(const uint4* pk, const float4* A0, const float4* A1, int lane){
    float m = 3.0e38f;
    #pragma unroll
    for (int it = 0; it < 3; ++it){
        float2 c0 = __half22float2(*(const __half2*)&pk[it].x);
        float2 c1 = __half22float2(*(const __half2*)&pk[it].y);
        float2 c2 = __half22float2(*(const __half2*)&pk[it].z);
        float2 c3 = __half22float2(*(const __half2*)&pk[it].w);
        m = fminf(m, fminf(fminf(A0[it].x - c0.x, A0[it].y - c0.y), fminf(A0[it].z - c1.x, A0[it].w - c1.y)));
        m = fminf(m, fminf(fminf(A1[it].x - c2.x, A1[it].y - c2.y), fminf(A1[it].z - c3.x, A1[it].w - c3.y)));
    }
    #pragma unroll
    for (int o = 1; o < 64; o <<= 1) m = fminf(m, __shfl_xor(m, o, 64));
    return m;
}

#define ROWPTR(PK, i) ((PK) + (size_t)((i) >> 7)*12*TILE + (size_t)((i) & 127)*128)

__global__ __launch_bounds__(1024, 1) void k_sink(const __half* __restrict__ P,
        float* __restrict__ fs, float* __restrict__ uvv,
        float* __restrict__ px0, float* __restrict__ px1,
        float* __restrict__ py0, float* __restrict__ py1,
        int* __restrict__ bars, int* __restrict__ flags,
        unsigned* __restrict__ cmin){
    int tid = threadIdx.x;
    int lane = tid & 63;
    int wid = tid >> 6;
    int blk = (int)blockIdx.x;
    __shared__ int s_ch;

    if (blk < 4*OTB){
        // ---------- OT group (fused colmin) ----------
        __shared__ unsigned lmin[1536];
        int b = blk / OTB, lb = blk - b*OTB;
        int gw = lb*16 + wid;
        const int NWV = OTB*16;     // 128 waves
        int* gbarp  = bars + b*64;
        int* gflagp = flags + b*64;
        const __half* P0 = P + (size_t)(b*4 + 0)*TSZ;
        float* fsb = fs + b*VSZ;
        float* uvb = uvv + b*VSZ;
        unsigned* cm = cmin + b*3*1536;

        int colb[3];
        #pragma unroll
        for (int it = 0; it < 3; ++it){
            int c = lane + it*64;
            colb[it] = ((c >> 4) << 7) + ((c & 15) << 3);
        }

        int lastT = 0;
        for (int t = 0; t < 30; ++t){
            unsigned* rdbuf = cm + ((t + 2) % 3)*1536;
            unsigned* wrbuf = cm + (t % 3)*1536;
            unsigned* rsbuf = cm + ((t + 1) % 3)*1536;
            if (tid == 0) s_ch = 0;
            for (int idx = tid; idx < 1536; idx += 1024) lmin[idx] = 0xFFFFFFFFu;
            float Au[3][8];
            #pragma unroll
            for (int it = 0; it < 3; ++it){
                uint4 k0 = *(const uint4*)(rdbuf + colb[it]);
                uint4 k1 = *(const uint4*)(rdbuf + colb[it] + 4);
                unsigned kk[8] = {k0.x, k0.y, k0.z, k0.w, k1.x, k1.y, k1.z, k1.w};
                #pragma unroll
                for (int e = 0; e < 8; ++e){
                    int col = colb[it] + e;
                    Au[it][e] = (col < NP) ? (-(funkey(kk[e]) + KADD)) : 3.0e38f;
                }
            }
            __syncthreads();
            float amin[3][8];
            #pragma unroll
            for (int it = 0; it < 3; ++it)
                #pragma unroll
                for (int e = 0; e < 8; ++e) amin[it][e] = 3.0e38f;
            int ch = 0;
            for (int i = gw; i < NP; i += NWV){
                const __half* rowb = ROWPTR(P0, i);
                uint4 pk[3];
                #pragma unroll
                for (int it = 0; it < 3; ++it){
                    int c = lane + it*64, tt = c >> 4, q = c & 15;
                    pk[it] = *(const uint4*)(rowb + (size_t)tt*TILE + q*8);
                }
                float cf[3][8];
                float m = 3.0e38f;
                #pragma unroll
                for (int it = 0; it < 3; ++it){
                    float2 c0 = __half22float2(*(const __half2*)&pk[it].x);
                    float2 c1 = __half22float2(*(const __half2*)&pk[it].y);
                    float2 c2 = __half22float2(*(const __half2*)&pk[it].z);
                    float2 c3 = __half22float2(*(const __half2*)&pk[it].w);
                    cf[it][0] = c0.x; cf[it][1] = c0.y; cf[it][2] = c1.x; cf[it][3] = c1.y;
                    cf[it][4] = c2.x; cf[it][5] = c2.y; cf[it][6] = c3.x; cf[it][7] = c3.y;
                    #pragma unroll
                    for (int e = 0; e < 8; ++e) m = fminf(m, Au[it][e] - cf[it][e]);
                }
                #pragma unroll
                for (int o = 1; o < 64; o <<= 1) m = fminf(m, __shfl_xor(m, o, 64));
                float nv = -(m + KADD);
                if (lane == 0){
                    if (fabsf(nv - fsb[i]) > FTHR) ch = 1;
                    fsb[i] = nv;
                }
                #pragma unroll
                for (int it = 0; it < 3; ++it)
                    #pragma unroll
                    for (int e = 0; e < 8; ++e)
                        amin[it][e] = fminf(amin[it][e], nv - cf[it][e]);
            }
            if (ch) s_ch = 1;
            #pragma unroll
            for (int it = 0; it < 3; ++it)
                #pragma unroll
                for (int e = 0; e < 8; ++e)
                    atomicMin(&lmin[colb[it] + e], fkey(amin[it][e]));
            __syncthreads();
            for (int idx = tid; idx < 1536; idx += 1024)
                atomicMin(&wrbuf[idx], lmin[idx]);
            if (tid < 192) rsbuf[lb*192 + tid] = 0xFFFFFFFFu;
            if (tid == 0 && s_ch) atomicOr(&gflagp[t], 1);
            groupbar(&gbarp[t], OTB);
            lastT = t;
            int fA = __hip_atomic_load(&gflagp[t], __ATOMIC_RELAXED, __HIP_MEMORY_SCOPE_AGENT);
            if (fA == 0) break;
        }
        unsigned* fin = cm + (lastT % 3)*1536;
        for (int j = tid; j < NP; j += 1024)
            uvb[j] = -(funkey(fin[j]) + KADD);
    } else {
        // ---------- self groups (full-row 2-deep) ----------
        int sg = blk - 4*OTB;
        int g = sg / SELFB, lb = sg - g*SELFB;
        int gw = lb*16 + wid;
        const int NWV = SELFB*16;   // 128 waves
        int b = g >> 1, kind = 2 + (g & 1);
        float* bufA = ((g & 1) ? py0 : px0) + b*VSZ;
        float* bufB = ((g & 1) ? py1 : px1) + b*VSZ;
        int* gbarp  = bars + (4 + g)*64;
        int* gflagp = flags + (4 + g)*64;
        const __half* PK = P + (size_t)(b*4 + kind)*TSZ;
        float4 A0[3], A1[3];
        uint4 pk0[3], pk1[3];
        for (int t = 0; t < 30; ++t){
            if (tid == 0) s_ch = 0;
            __syncthreads();
            {
                int ch = 0;
                loadvec(bufA, A0, A1, lane);
                for (int i = gw; i < NP; i += 2*NWV){
                    int i2 = i + NWV;
                    loadrow(ROWPTR(PK, i), lane, pk0);
                    if (i2 < NP) loadrow(ROWPTR(PK, i2), lane, pk1);
                    float m = redrow(pk0, A0, A1, lane);
                    if (lane == 0){
                        float ov = bufA[i];
                        float nv = 0.5f*(ov - m - KADD);
                        if (fabsf(nv - ov) > FTHR) ch = 1;
                        bufB[i] = nv;
                    }
                    if (i2 < NP){
                        float m2 = redrow(pk1, A0, A1, lane);
                        if (lane == 0){
                            float ov = bufA[i2];
                            float nv = 0.5f*(ov - m2 - KADD);
                            if (fabsf(nv - ov) > FTHR) ch = 1;
                            bufB[i2] = nv;
                        }
                    }
                }
                if (ch) s_ch = 1;
            }
            __syncthreads();
            if (tid == 0 && s_ch) atomicOr(&gflagp[t], 1);
            groupbar(&gbarp[t], SELFB);
            int fC = __hip_atomic_load(&gflagp[t], __ATOMIC_RELAXED, __HIP_MEMORY_SCOPE_AGENT);
            if (fC == 0) break;
            { float* tmp = bufA; bufA = bufB; bufB = tmp; }
        }
    }
}

// S = (4/1500) * sum_b,i (psxx + psyy - fs - u)
__global__ void k_final(const float* __restrict__ fs, const float* __restrict__ u,
                        const float* __restrict__ psxx, const float* __restrict__ psyy,
                        float* __restrict__ out){
    __shared__ double red[256];
    double s = 0.0;
    for (int t = threadIdx.x; t < NB*NP; t += 256){
        int b = t / NP, i = t - b*NP; int o = b*VSZ + i;
        s += (double)psxx[o] + (double)psyy[o] - (double)fs[o] - (double)u[o];
    }
    red[threadIdx.x] = s; __syncthreads();
    for (int w = 128; w > 0; w >>= 1){
        if (threadIdx.x < w) red[threadIdx.x] += red[threadIdx.x + w];
        __syncthreads();
    }
    if (threadIdx.x == 0) out[0] = (float)(red[0] * (4.0/1500.0));
}

extern "C" void kernel_launch(void* const* d_in, const int* in_sizes, int n_in,
                              void* d_out, int out_size, void* d_ws, size_t ws_size,
                              hipStream_t stream) {
    const float* x = (const float*)d_in[0];
    const float* y = (const float*)d_in[1];
    float* out = (float*)d_out;

    __half* pxh = (__half*)d_ws;
    __half* pyh = pxh + (size_t)NB*NP*DP;
    float* csx = (float*)(pyh + (size_t)NB*NP*DP);
    float* csy = csx + NB*DD;
    float* fs  = csy + NB*DD;
    float* uv  = fs + NB*VSZ;
    float* px0 = uv + NB*VSZ;
    float* px1 = px0 + NB*VSZ;
    float* py0 = px1 + NB*VSZ;
    float* py1 = py0 + NB*VSZ;
    int* bars  = (int*)(py1 + NB*VSZ);                 // 12*64 ints
    int* flags = bars + 12*64;                         // 12*64 ints
    unsigned* cmin = (unsigned*)(flags + 12*64);       // 4*3*1536 uints
    float* partial = (float*)(cmin + 4*3*1536);        // 12*NB*2*DD floats
    float* smallEnd = partial + (size_t)12*NB*2*DD;
    size_t pOff = (((size_t)((char*)smallEnd - (char*)d_ws)) + 255) & ~(size_t)255;
    __half* P = (__half*)((char*)d_ws + pOff);

    int nzero = (int)(((float*)(flags + 12*64)) - csx);
    int nkeys = 4*3*1536;
    k_init<<<(nzero + nkeys + 255)/256, 256, 0, stream>>>(csx, nzero, cmin, nkeys);

    k_colsum_p1<<<dim3(12, NB, 2), 256, 0, stream>>>(x, y, partial);
    k_colsum_p2<<<10, 256, 0, stream>>>(partial, csx, csy);

    k_normrow<<<3000, 256, 0, stream>>>(x, y, csx, csy, pxh, pyh, px0, uv, py0, cmin);

    k_gemm_mfma<<<dim3(12, 12, 12), 256, 0, stream>>>(pxh, pyh, P);

    k_sink<<<4*OTB + 8*SELFB, 1024, 0, stream>>>(P, fs, uv, px0, px1, py0, py1, bars, flags, cmin);

    k_final<<<1, 256, 0, stream>>>(fs, uv, px0, py0, out);
}

// Round 22
// 176.042 us; speedup vs baseline: 1.1508x; 1.0628x over previous
//
// v17 — v16 with sink groups scaled to fill the chip: OTB=16 (256 waves/OT group),
// SELFB=12 (192 waves/self group), 160 blocks x 1024 thr (1 block/CU, was 96/256 CUs).
// Reset stripe 1536/16=96. Everything else identical to v16 (best: 187.1).
#include <hip/hip_runtime.h>
#include <hip/hip_fp16.h>

#define NP 1500
#define DD 300
#define DP 320
#define VSZ 1536
#define NB 4
#define TILE 16384
#define TSZ (1536*1536)
#define OTB 16              // blocks per OT group
#define SELFB 12            // blocks per self group
#define KADD 1.8283051e-8f
#define PADVAL (-60000.0f)
#define SCALE 256.0f
#define SCALE2INV (1.0f/65536.0f)
#define FTHR 1e-8f

typedef _Float16 f16x8 __attribute__((ext_vector_type(8)));
typedef float f32x4 __attribute__((ext_vector_type(4)));

__device__ __forceinline__ unsigned fkey(float f){
    unsigned b = __float_as_uint(f);
    return (b & 0x80000000u) ? ~b : (b | 0x80000000u);
}
__device__ __forceinline__ float funkey(unsigned k){
    unsigned b = (k & 0x80000000u) ? (k & 0x7FFFFFFFu) : ~k;
    return __uint_as_float(b);
}

// zero nz floats then set nk uints to 0xFFFFFFFF (one launch)
__global__ void k_init(float* pz, int nz, unsigned* pk, int nk){
    int i = blockIdx.x*blockDim.x + threadIdx.x;
    if (i < nz) pz[i] = 0.f;
    int j = i - nz;
    if (j >= 0 && j < nk) pk[j] = 0xFFFFFFFFu;
}

// ---- deterministic column sums ----
__global__ __launch_bounds__(256) void k_colsum_p1(const float* __restrict__ x, const float* __restrict__ y,
                                                   float* __restrict__ partial){
    int rc = blockIdx.x, b = blockIdx.y, src = blockIdx.z;
    const float* in = (src ? y : x) + ((size_t)b*NP + rc*125)*DD;
    int tid = threadIdx.x;
    float s0 = 0.f, s1 = 0.f;
    #pragma unroll 4
    for (int r = 0; r < 125; ++r){
        float v0 = in[r*DD + tid];
        s0 = fmaf(v0, v0, s0);
        if (tid < 44){
            float v1 = in[r*DD + 256 + tid];
            s1 = fmaf(v1, v1, s1);
        }
    }
    float* po = partial + (((size_t)rc*NB + b)*2 + src)*DD;
    po[tid] = s0;
    if (tid < 44) po[256 + tid] = s1;
}

__global__ void k_colsum_p2(const float* __restrict__ partial,
                            float* __restrict__ csx, float* __restrict__ csy){
    int idx = blockIdx.x*256 + threadIdx.x;
    if (idx >= NB*2*DD) return;
    int c = idx % DD; int t = idx / DD; int src = t & 1; int b = t >> 1;
    float s = 0.f;
    #pragma unroll
    for (int rc = 0; rc < 12; ++rc)
        s += partial[(((size_t)rc*NB + b)*2 + src)*DD + c];
    (src ? csy : csx)[b*DD + c] = s;
}

// ---- normalize + row-norm init; side1 seeds OT cmin buffer 2 with fkey(-(ynrm+KADD)) ----
__global__ __launch_bounds__(256) void k_normrow(const float* __restrict__ x, const float* __restrict__ y,
        const float* __restrict__ csx, const float* __restrict__ csy,
        __half* __restrict__ pxh, __half* __restrict__ pyh,
        float* __restrict__ psxx0, float* __restrict__ uvv, float* __restrict__ psyy0,
        unsigned* __restrict__ cmin){
    int gw = ((int)blockIdx.x*256 + threadIdx.x) >> 6;
    int lane = threadIdx.x & 63;
    int src = (gw >= NB*NP) ? 1 : 0;
    int rem = gw - src*NB*NP;
    int b = rem / NP, i = rem - b*NP;
    const float* in = (src ? y : x) + ((size_t)b*NP + i)*DD;
    const float* cs = (src ? csy : csx) + b*DD;
    __half* oph = (src ? pyh : pxh) + ((size_t)b*NP + i)*DP;
    float s = 0.f;
    #pragma unroll
    for (int it = 0; it < 5; ++it){
        int c = lane + it*64;
        float vu = 0.f, hv = 0.f;
        if (c < DD){
            float u = in[c];
            vu = u*u / cs[c];
            hv = vu * SCALE;
        }
        oph[c] = __float2half(hv);
        s = fmaf(vu, vu, s);
    }
    #pragma unroll
    for (int o2 = 1; o2 < 64; o2 <<= 1) s += __shfl_xor(s, o2, 64);
    if (lane == 0){
        float val = 0.5f * s;
        int o = b*VSZ + i;
        if (src){
            uvv[o] = val; psyy0[o] = val;
            cmin[(b*3 + 2)*1536 + i] = fkey(-(val + KADD));
        } else {
            psxx0[o] = val;
        }
    }
}

// ---- MFMA GEMM: BK=64, prefetch, swizzled LDS, plain stores. kinds {0,2,3} ----
__global__ __launch_bounds__(256) void k_gemm_mfma(const __half* __restrict__ pxh,
                                                   const __half* __restrict__ pyh,
                                                   __half* __restrict__ P){
    int z = blockIdx.z; int b = z/3; int kidx = z - b*3;
    int kind = (kidx==0) ? 0 : ((kidx==1) ? 2 : 3);
    int bx = blockIdx.x, by = blockIdx.y;
    if (kind != 0 && by > bx) return;
    const __half* A = (((kind==0)||(kind==2)) ? pxh : pyh) + (size_t)b*NP*DP;
    const __half* B = (((kind==0)||(kind==3)) ? pyh : pxh) + (size_t)b*NP*DP;

    __shared__ __align__(16) char smem[128*136*2];
    char* ldsA = smem;
    char* ldsB = smem + 16384;
    __half* ldsO = (__half*)smem;

    int tid = threadIdx.x;
    int row0 = bx*128, col0 = by*128;
    int lane = tid & 63;
    int w = tid >> 6;
    int wm = (w >> 1)*64, wn = (w & 1)*64;
    int g8 = tid & 7, rw = tid >> 3;
    int lr = lane & 15, cq = lane >> 4;

    f32x4 acc[4][4];
    #pragma unroll
    for (int mi = 0; mi < 4; ++mi)
        #pragma unroll
        for (int ni = 0; ni < 4; ++ni)
            acc[mi][ni] = (f32x4){0.f, 0.f, 0.f, 0.f};

    uint4 va[4], vb[4];
    #pragma unroll
    for (int is = 0; is < 4; ++is){
        int r = rw + is*32;
        int ar = row0 + r; if (ar > NP-1) ar = NP-1;
        int br = col0 + r; if (br > NP-1) br = NP-1;
        va[is] = *(const uint4*)(A + (size_t)ar*DP + g8*8);
        vb[is] = *(const uint4*)(B + (size_t)br*DP + g8*8);
    }
    #pragma unroll
    for (int ks = 0; ks < 5; ++ks){
        if (ks) __syncthreads();
        #pragma unroll
        for (int is = 0; is < 4; ++is){
            int r = rw + is*32;
            int pc = g8 ^ (r & 7);
            *(uint4*)(ldsA + r*128 + pc*16) = va[is];
            *(uint4*)(ldsB + r*128 + pc*16) = vb[is];
        }
        __syncthreads();
        if (ks < 4){
            int k0 = (ks + 1)*64;
            #pragma unroll
            for (int is = 0; is < 4; ++is){
                int r = rw + is*32;
                int ar = row0 + r; if (ar > NP-1) ar = NP-1;
                int br = col0 + r; if (br > NP-1) br = NP-1;
                va[is] = *(const uint4*)(A + (size_t)ar*DP + k0 + g8*8);
                vb[is] = *(const uint4*)(B + (size_t)br*DP + k0 + g8*8);
            }
        }
        f16x8 av[2][4], bv[2][4];
        #pragma unroll
        for (int ksl = 0; ksl < 2; ++ksl){
            int lc = ksl*4 + cq;
            int pc = (lc ^ (lr & 7))*16;
            #pragma unroll
            for (int mi = 0; mi < 4; ++mi)
                av[ksl][mi] = *(const f16x8*)(ldsA + (wm + mi*16 + lr)*128 + pc);
            #pragma unroll
            for (int ni = 0; ni < 4; ++ni)
                bv[ksl][ni] = *(const f16x8*)(ldsB + (wn + ni*16 + lr)*128 + pc);
        }
        #pragma unroll
        for (int ksl = 0; ksl < 2; ++ksl)
            #pragma unroll
            for (int mi = 0; mi < 4; ++mi)
                #pragma unroll
                for (int ni = 0; ni < 4; ++ni)
                    acc[mi][ni] = __builtin_amdgcn_mfma_f32_16x16x32_f16(av[ksl][mi], bv[ksl][ni], acc[mi][ni], 0, 0, 0);
    }

    int cqe = lane >> 4;
    __syncthreads();
    #pragma unroll
    for (int mi = 0; mi < 4; ++mi)
        #pragma unroll
        for (int ni = 0; ni < 4; ++ni){
            int lcol = wn + ni*16 + lr;
            bool colok = (col0 + lcol) < NP;
            #pragma unroll
            for (int v = 0; v < 4; ++v){
                int lrow = wm + mi*16 + cqe*4 + v;
                bool rowok = (row0 + lrow) < NP;
                ldsO[lrow*136 + lcol] = __float2half((colok && rowok) ? acc[mi][ni][v]*SCALE2INV : PADVAL);
            }
        }
    __syncthreads();
    {
        __half* tileD = P + (size_t)(b*4 + kind)*TSZ + ((size_t)bx*12 + by)*TILE;
        #pragma unroll
        for (int it = 0; it < 8; ++it){
            int e = it*256 + tid;
            int r = e >> 4, q = e & 15;
            *(uint4*)(tileD + r*128 + q*8) = *(const uint4*)(ldsO + r*136 + q*8);
        }
    }
    if (kind != 0 && bx != by){
        __syncthreads();
        #pragma unroll
        for (int mi = 0; mi < 4; ++mi)
            #pragma unroll
            for (int ni = 0; ni < 4; ++ni){
                int trow = wn + ni*16 + lr;
                bool colok = (col0 + trow) < NP;
                #pragma unroll
                for (int v = 0; v < 4; ++v){
                    int tcol = wm + mi*16 + cqe*4 + v;
                    bool rowok = (row0 + tcol) < NP;
                    ldsO[trow*136 + tcol] = __float2half((rowok && colok) ? acc[mi][ni][v]*SCALE2INV : PADVAL);
                }
            }
        __syncthreads();
        __half* tileT = P + (size_t)(b*4 + kind)*TSZ + ((size_t)by*12 + bx)*TILE;
        #pragma unroll
        for (int it = 0; it < 8; ++it){
            int e = it*256 + tid;
            int r = e >> 4, q = e & 15;
            *(uint4*)(tileT + r*128 + q*8) = *(const uint4*)(ldsO + r*136 + q*8);
        }
    }
}

// ---- persistent Sinkhorn: OT fused colmin (16 blks/grp); self full-row 2-deep (12 blks/grp) ----
__device__ __forceinline__ void groupbar(int* slot, int gsz){
    __syncthreads();
    if (threadIdx.x == 0){
        __hip_atomic_fetch_add(slot, 1, __ATOMIC_RELEASE, __HIP_MEMORY_SCOPE_AGENT);
        while (__hip_atomic_load(slot, __ATOMIC_ACQUIRE, __HIP_MEMORY_SCOPE_AGENT) < gsz)
            __builtin_amdgcn_s_sleep(1);
    }
    __syncthreads();
}

__device__ __forceinline__ void loadvec(const float* __restrict__ v, float4* A0, float4* A1, int lane){
    const float4* a4 = (const float4*)v;
    #pragma unroll
    for (int it = 0; it < 3; ++it){
        int c = lane + it*64, tt = c >> 4, q = c & 15;
        A0[it] = a4[tt*32 + q*2];
        A1[it] = a4[tt*32 + q*2 + 1];
    }
}

__device__ __forceinline__ void loadrow(const __half* __restrict__ rowb, int lane, uint4* pk){
    #pragma unroll
    for (int it = 0; it < 3; ++it){
        int c = lane + it*64, tt = c >> 4, q = c & 15;
        pk[it] = *(const uint4*)(rowb + (size_t)tt*TILE + q*8);
    }
}

__device__ __forceinline__ float redrow(const uint4* pk, const float4* A0, const float4* A1, int lane){
    float m = 3.0e38f;
    #pragma unroll
    for (int it = 0; it < 3; ++it){
        float2 c0 = __half22float2(*(const __half2*)&pk[it].x);
        float2 c1 = __half22float2(*(const __half2*)&pk[it].y);
        float2 c2 = __half22float2(*(const __half2*)&pk[it].z);
        float2 c3 = __half22float2(*(const __half2*)&pk[it].w);
        m = fminf(m, fminf(fminf(A0[it].x - c0.x, A0[it].y - c0.y), fminf(A0[it].z - c1.x, A0[it].w - c1.y)));
        m = fminf(m, fminf(fminf(A1[it].x - c2.x, A1[it].y - c2.y), fminf(A1[it].z - c3.x, A1[it].w - c3.y)));
    }
    #pragma unroll
    for (int o = 1; o < 64; o <<= 1) m = fminf(m, __shfl_xor(m, o, 64));
    return m;
}

#define ROWPTR(PK, i) ((PK) + (size_t)((i) >> 7)*12*TILE + (size_t)((i) & 127)*128)

__global__ __launch_bounds__(1024, 1) void k_sink(const __half* __restrict__ P,
        float* __restrict__ fs, float* __restrict__ uvv,
        float* __restrict__ px0, float* __restrict__ px1,
        float* __restrict__ py0, float* __restrict__ py1,
        int* __restrict__ bars, int* __restrict__ flags,
        unsigned* __restrict__ cmin){
    int tid = threadIdx.x;
    int lane = tid & 63;
    int wid = tid >> 6;
    int blk = (int)blockIdx.x;
    __shared__ int s_ch;

    if (blk < 4*OTB){
        // ---------- OT group (fused colmin) ----------
        __shared__ unsigned lmin[1536];
        int b = blk / OTB, lb = blk - b*OTB;
        int gw = lb*16 + wid;
        const int NWV = OTB*16;     // 256 waves
        int* gbarp  = bars + b*64;
        int* gflagp = flags + b*64;
        const __half* P0 = P + (size_t)(b*4 + 0)*TSZ;
        float* fsb = fs + b*VSZ;
        float* uvb = uvv + b*VSZ;
        unsigned* cm = cmin + b*3*1536;

        int colb[3];
        #pragma unroll
        for (int it = 0; it < 3; ++it){
            int c = lane + it*64;
            colb[it] = ((c >> 4) << 7) + ((c & 15) << 3);
        }

        int lastT = 0;
        for (int t = 0; t < 30; ++t){
            unsigned* rdbuf = cm + ((t + 2) % 3)*1536;
            unsigned* wrbuf = cm + (t % 3)*1536;
            unsigned* rsbuf = cm + ((t + 1) % 3)*1536;
            if (tid == 0) s_ch = 0;
            for (int idx = tid; idx < 1536; idx += 1024) lmin[idx] = 0xFFFFFFFFu;
            float Au[3][8];
            #pragma unroll
            for (int it = 0; it < 3; ++it){
                uint4 k0 = *(const uint4*)(rdbuf + colb[it]);
                uint4 k1 = *(const uint4*)(rdbuf + colb[it] + 4);
                unsigned kk[8] = {k0.x, k0.y, k0.z, k0.w, k1.x, k1.y, k1.z, k1.w};
                #pragma unroll
                for (int e = 0; e < 8; ++e){
                    int col = colb[it] + e;
                    Au[it][e] = (col < NP) ? (-(funkey(kk[e]) + KADD)) : 3.0e38f;
                }
            }
            __syncthreads();
            float amin[3][8];
            #pragma unroll
            for (int it = 0; it < 3; ++it)
                #pragma unroll
                for (int e = 0; e < 8; ++e) amin[it][e] = 3.0e38f;
            int ch = 0;
            for (int i = gw; i < NP; i += NWV){
                const __half* rowb = ROWPTR(P0, i);
                uint4 pk[3];
                #pragma unroll
                for (int it = 0; it < 3; ++it){
                    int c = lane + it*64, tt = c >> 4, q = c & 15;
                    pk[it] = *(const uint4*)(rowb + (size_t)tt*TILE + q*8);
                }
                float cf[3][8];
                float m = 3.0e38f;
                #pragma unroll
                for (int it = 0; it < 3; ++it){
                    float2 c0 = __half22float2(*(const __half2*)&pk[it].x);
                    float2 c1 = __half22float2(*(const __half2*)&pk[it].y);
                    float2 c2 = __half22float2(*(const __half2*)&pk[it].z);
                    float2 c3 = __half22float2(*(const __half2*)&pk[it].w);
                    cf[it][0] = c0.x; cf[it][1] = c0.y; cf[it][2] = c1.x; cf[it][3] = c1.y;
                    cf[it][4] = c2.x; cf[it][5] = c2.y; cf[it][6] = c3.x; cf[it][7] = c3.y;
                    #pragma unroll
                    for (int e = 0; e < 8; ++e) m = fminf(m, Au[it][e] - cf[it][e]);
                }
                #pragma unroll
                for (int o = 1; o < 64; o <<= 1) m = fminf(m, __shfl_xor(m, o, 64));
                float nv = -(m + KADD);
                if (lane == 0){
                    if (fabsf(nv - fsb[i]) > FTHR) ch = 1;
                    fsb[i] = nv;
                }
                #pragma unroll
                for (int it = 0; it < 3; ++it)
                    #pragma unroll
                    for (int e = 0; e < 8; ++e)
                        amin[it][e] = fminf(amin[it][e], nv - cf[it][e]);
            }
            if (ch) s_ch = 1;
            #pragma unroll
            for (int it = 0; it < 3; ++it)
                #pragma unroll
                for (int e = 0; e < 8; ++e)
                    atomicMin(&lmin[colb[it] + e], fkey(amin[it][e]));
            __syncthreads();
            for (int idx = tid; idx < 1536; idx += 1024)
                atomicMin(&wrbuf[idx], lmin[idx]);
            if (tid < 96) rsbuf[lb*96 + tid] = 0xFFFFFFFFu;
            if (tid == 0 && s_ch) atomicOr(&gflagp[t], 1);
            groupbar(&gbarp[t], OTB);
            lastT = t;
            int fA = __hip_atomic_load(&gflagp[t], __ATOMIC_RELAXED, __HIP_MEMORY_SCOPE_AGENT);
            if (fA == 0) break;
        }
        unsigned* fin = cm + (lastT % 3)*1536;
        for (int j = tid; j < NP; j += 1024)
            uvb[j] = -(funkey(fin[j]) + KADD);
    } else {
        // ---------- self groups (full-row 2-deep) ----------
        int sg = blk - 4*OTB;
        int g = sg / SELFB, lb = sg - g*SELFB;
        int gw = lb*16 + wid;
        const int NWV = SELFB*16;   // 192 waves
        int b = g >> 1, kind = 2 + (g & 1);
        float* bufA = ((g & 1) ? py0 : px0) + b*VSZ;
        float* bufB = ((g & 1) ? py1 : px1) + b*VSZ;
        int* gbarp  = bars + (4 + g)*64;
        int* gflagp = flags + (4 + g)*64;
        const __half* PK = P + (size_t)(b*4 + kind)*TSZ;
        float4 A0[3], A1[3];
        uint4 pk0[3], pk1[3];
        for (int t = 0; t < 30; ++t){
            if (tid == 0) s_ch = 0;
            __syncthreads();
            {
                int ch = 0;
                loadvec(bufA, A0, A1, lane);
                for (int i = gw; i < NP; i += 2*NWV){
                    int i2 = i + NWV;
                    loadrow(ROWPTR(PK, i), lane, pk0);
                    if (i2 < NP) loadrow(ROWPTR(PK, i2), lane, pk1);
                    float m = redrow(pk0, A0, A1, lane);
                    if (lane == 0){
                        float ov = bufA[i];
                        float nv = 0.5f*(ov - m - KADD);
                        if (fabsf(nv - ov) > FTHR) ch = 1;
                        bufB[i] = nv;
                    }
                    if (i2 < NP){
                        float m2 = redrow(pk1, A0, A1, lane);
                        if (lane == 0){
                            float ov = bufA[i2];
                            float nv = 0.5f*(ov - m2 - KADD);
                            if (fabsf(nv - ov) > FTHR) ch = 1;
                            bufB[i2] = nv;
                        }
                    }
                }
                if (ch) s_ch = 1;
            }
            __syncthreads();
            if (tid == 0 && s_ch) atomicOr(&gflagp[t], 1);
            groupbar(&gbarp[t], SELFB);
            int fC = __hip_atomic_load(&gflagp[t], __ATOMIC_RELAXED, __HIP_MEMORY_SCOPE_AGENT);
            if (fC == 0) break;
            { float* tmp = bufA; bufA = bufB; bufB = tmp; }
        }
    }
}

// S = (4/1500) * sum_b,i (psxx + psyy - fs - u)
__global__ void k_final(const float* __restrict__ fs, const float* __restrict__ u,
                        const float* __restrict__ psxx, const float* __restrict__ psyy,
                        float* __restrict__ out){
    __shared__ double red[256];
    double s = 0.0;
    for (int t = threadIdx.x; t < NB*NP; t += 256){
        int b = t / NP, i = t - b*NP; int o = b*VSZ + i;
        s += (double)psxx[o] + (double)psyy[o] - (double)fs[o] - (double)u[o];
    }
    red[threadIdx.x] = s; __syncthreads();
    for (int w = 128; w > 0; w >>= 1){
        if (threadIdx.x < w) red[threadIdx.x] += red[threadIdx.x + w];
        __syncthreads();
    }
    if (threadIdx.x == 0) out[0] = (float)(red[0] * (4.0/1500.0));
}

extern "C" void kernel_launch(void* const* d_in, const int* in_sizes, int n_in,
                              void* d_out, int out_size, void* d_ws, size_t ws_size,
                              hipStream_t stream) {
    const float* x = (const float*)d_in[0];
    const float* y = (const float*)d_in[1];
    float* out = (float*)d_out;

    __half* pxh = (__half*)d_ws;
    __half* pyh = pxh + (size_t)NB*NP*DP;
    float* csx = (float*)(pyh + (size_t)NB*NP*DP);
    float* csy = csx + NB*DD;
    float* fs  = csy + NB*DD;
    float* uv  = fs + NB*VSZ;
    float* px0 = uv + NB*VSZ;
    float* px1 = px0 + NB*VSZ;
    float* py0 = px1 + NB*VSZ;
    float* py1 = py0 + NB*VSZ;
    int* bars  = (int*)(py1 + NB*VSZ);                 // 12*64 ints
    int* flags = bars + 12*64;                         // 12*64 ints
    unsigned* cmin = (unsigned*)(flags + 12*64);       // 4*3*1536 uints
    float* partial = (float*)(cmin + 4*3*1536);        // 12*NB*2*DD floats
    float* smallEnd = partial + (size_t)12*NB*2*DD;
    size_t pOff = (((size_t)((char*)smallEnd - (char*)d_ws)) + 255) & ~(size_t)255;
    __half* P = (__half*)((char*)d_ws + pOff);

    int nzero = (int)(((float*)(flags + 12*64)) - csx);
    int nkeys = 4*3*1536;
    k_init<<<(nzero + nkeys + 255)/256, 256, 0, stream>>>(csx, nzero, cmin, nkeys);

    k_colsum_p1<<<dim3(12, NB, 2), 256, 0, stream>>>(x, y, partial);
    k_colsum_p2<<<10, 256, 0, stream>>>(partial, csx, csy);

    k_normrow<<<3000, 256, 0, stream>>>(x, y, csx, csy, pxh, pyh, px0, uv, py0, cmin);

    k_gemm_mfma<<<dim3(12, 12, 12), 256, 0, stream>>>(pxh, pyh, P);

    k_sink<<<4*OTB + 8*SELFB, 1024, 0, stream>>>(P, fs, uv, px0, px1, py0, py1, bars, flags, cmin);

    k_final<<<1, 256, 0, stream>>>(fs, uv, px0, py0, out);
}

// Round 23
// 134.625 us; speedup vs baseline: 1.5049x; 1.3077x over previous
//
// v18 — self-potentials eliminated mathematically (hard-min fixed point p* ≈ 0 within
// eps·lnN·30 ≈ 2.8e-7; dropped error ~9e-6 << 6.5e-5 threshold). GEMM = kind0 only
// (576 blocks); sink = 4 OT groups only (64 blocks); k_final uses xnrm/ynrm directly.
// OT path identical to v17 (best: 176.0).
#include <hip/hip_runtime.h>
#include <hip/hip_fp16.h>

#define NP 1500
#define DD 300
#define DP 320
#define VSZ 1536
#define NB 4
#define TILE 16384
#define TSZ (1536*1536)
#define OTB 16              // blocks per OT group
#define KADD 1.8283051e-8f
#define PADVAL (-60000.0f)
#define SCALE 256.0f
#define SCALE2INV (1.0f/65536.0f)
#define FTHR 1e-8f

typedef _Float16 f16x8 __attribute__((ext_vector_type(8)));
typedef float f32x4 __attribute__((ext_vector_type(4)));

__device__ __forceinline__ unsigned fkey(float f){
    unsigned b = __float_as_uint(f);
    return (b & 0x80000000u) ? ~b : (b | 0x80000000u);
}
__device__ __forceinline__ float funkey(unsigned k){
    unsigned b = (k & 0x80000000u) ? (k & 0x7FFFFFFFu) : ~k;
    return __uint_as_float(b);
}

// zero nz floats then set nk uints to 0xFFFFFFFF (one launch)
__global__ void k_init(float* pz, int nz, unsigned* pk, int nk){
    int i = blockIdx.x*blockDim.x + threadIdx.x;
    if (i < nz) pz[i] = 0.f;
    int j = i - nz;
    if (j >= 0 && j < nk) pk[j] = 0xFFFFFFFFu;
}

// ---- deterministic column sums ----
__global__ __launch_bounds__(256) void k_colsum_p1(const float* __restrict__ x, const float* __restrict__ y,
                                                   float* __restrict__ partial){
    int rc = blockIdx.x, b = blockIdx.y, src = blockIdx.z;
    const float* in = (src ? y : x) + ((size_t)b*NP + rc*125)*DD;
    int tid = threadIdx.x;
    float s0 = 0.f, s1 = 0.f;
    #pragma unroll 4
    for (int r = 0; r < 125; ++r){
        float v0 = in[r*DD + tid];
        s0 = fmaf(v0, v0, s0);
        if (tid < 44){
            float v1 = in[r*DD + 256 + tid];
            s1 = fmaf(v1, v1, s1);
        }
    }
    float* po = partial + (((size_t)rc*NB + b)*2 + src)*DD;
    po[tid] = s0;
    if (tid < 44) po[256 + tid] = s1;
}

__global__ void k_colsum_p2(const float* __restrict__ partial,
                            float* __restrict__ csx, float* __restrict__ csy){
    int idx = blockIdx.x*256 + threadIdx.x;
    if (idx >= NB*2*DD) return;
    int c = idx % DD; int t = idx / DD; int src = t & 1; int b = t >> 1;
    float s = 0.f;
    #pragma unroll
    for (int rc = 0; rc < 12; ++rc)
        s += partial[(((size_t)rc*NB + b)*2 + src)*DD + c];
    (src ? csy : csx)[b*DD + c] = s;
}

// ---- normalize + row-norm init; side1 seeds OT cmin buffer 2 with fkey(-(ynrm+KADD)) ----
__global__ __launch_bounds__(256) void k_normrow(const float* __restrict__ x, const float* __restrict__ y,
        const float* __restrict__ csx, const float* __restrict__ csy,
        __half* __restrict__ pxh, __half* __restrict__ pyh,
        float* __restrict__ xnrm, float* __restrict__ uvv, float* __restrict__ ynrm,
        unsigned* __restrict__ cmin){
    int gw = ((int)blockIdx.x*256 + threadIdx.x) >> 6;
    int lane = threadIdx.x & 63;
    int src = (gw >= NB*NP) ? 1 : 0;
    int rem = gw - src*NB*NP;
    int b = rem / NP, i = rem - b*NP;
    const float* in = (src ? y : x) + ((size_t)b*NP + i)*DD;
    const float* cs = (src ? csy : csx) + b*DD;
    __half* oph = (src ? pyh : pxh) + ((size_t)b*NP + i)*DP;
    float s = 0.f;
    #pragma unroll
    for (int it = 0; it < 5; ++it){
        int c = lane + it*64;
        float vu = 0.f, hv = 0.f;
        if (c < DD){
            float u = in[c];
            vu = u*u / cs[c];
            hv = vu * SCALE;
        }
        oph[c] = __float2half(hv);
        s = fmaf(vu, vu, s);
    }
    #pragma unroll
    for (int o2 = 1; o2 < 64; o2 <<= 1) s += __shfl_xor(s, o2, 64);
    if (lane == 0){
        float val = 0.5f * s;
        int o = b*VSZ + i;
        if (src){
            uvv[o] = val; ynrm[o] = val;
            cmin[(b*3 + 2)*1536 + i] = fkey(-(val + KADD));
        } else {
            xnrm[o] = val;
        }
    }
}

// ---- MFMA GEMM: kind0 (Pxy) ONLY. BK=64, prefetch, swizzled LDS, plain stores ----
__global__ __launch_bounds__(256) void k_gemm_mfma(const __half* __restrict__ pxh,
                                                   const __half* __restrict__ pyh,
                                                   __half* __restrict__ P){
    int b = blockIdx.z;
    int bx = blockIdx.x, by = blockIdx.y;
    const __half* A = pxh + (size_t)b*NP*DP;
    const __half* B = pyh + (size_t)b*NP*DP;

    __shared__ __align__(16) char smem[128*136*2];
    char* ldsA = smem;
    char* ldsB = smem + 16384;
    __half* ldsO = (__half*)smem;

    int tid = threadIdx.x;
    int row0 = bx*128, col0 = by*128;
    int lane = tid & 63;
    int w = tid >> 6;
    int wm = (w >> 1)*64, wn = (w & 1)*64;
    int g8 = tid & 7, rw = tid >> 3;
    int lr = lane & 15, cq = lane >> 4;

    f32x4 acc[4][4];
    #pragma unroll
    for (int mi = 0; mi < 4; ++mi)
        #pragma unroll
        for (int ni = 0; ni < 4; ++ni)
            acc[mi][ni] = (f32x4){0.f, 0.f, 0.f, 0.f};

    uint4 va[4], vb[4];
    #pragma unroll
    for (int is = 0; is < 4; ++is){
        int r = rw + is*32;
        int ar = row0 + r; if (ar > NP-1) ar = NP-1;
        int br = col0 + r; if (br > NP-1) br = NP-1;
        va[is] = *(const uint4*)(A + (size_t)ar*DP + g8*8);
        vb[is] = *(const uint4*)(B + (size_t)br*DP + g8*8);
    }
    #pragma unroll
    for (int ks = 0; ks < 5; ++ks){
        if (ks) __syncthreads();
        #pragma unroll
        for (int is = 0; is < 4; ++is){
            int r = rw + is*32;
            int pc = g8 ^ (r & 7);
            *(uint4*)(ldsA + r*128 + pc*16) = va[is];
            *(uint4*)(ldsB + r*128 + pc*16) = vb[is];
        }
        __syncthreads();
        if (ks < 4){
            int k0 = (ks + 1)*64;
            #pragma unroll
            for (int is = 0; is < 4; ++is){
                int r = rw + is*32;
                int ar = row0 + r; if (ar > NP-1) ar = NP-1;
                int br = col0 + r; if (br > NP-1) br = NP-1;
                va[is] = *(const uint4*)(A + (size_t)ar*DP + k0 + g8*8);
                vb[is] = *(const uint4*)(B + (size_t)br*DP + k0 + g8*8);
            }
        }
        f16x8 av[2][4], bv[2][4];
        #pragma unroll
        for (int ksl = 0; ksl < 2; ++ksl){
            int lc = ksl*4 + cq;
            int pc = (lc ^ (lr & 7))*16;
            #pragma unroll
            for (int mi = 0; mi < 4; ++mi)
                av[ksl][mi] = *(const f16x8*)(ldsA + (wm + mi*16 + lr)*128 + pc);
            #pragma unroll
            for (int ni = 0; ni < 4; ++ni)
                bv[ksl][ni] = *(const f16x8*)(ldsB + (wn + ni*16 + lr)*128 + pc);
        }
        #pragma unroll
        for (int ksl = 0; ksl < 2; ++ksl)
            #pragma unroll
            for (int mi = 0; mi < 4; ++mi)
                #pragma unroll
                for (int ni = 0; ni < 4; ++ni)
                    acc[mi][ni] = __builtin_amdgcn_mfma_f32_16x16x32_f16(av[ksl][mi], bv[ksl][ni], acc[mi][ni], 0, 0, 0);
    }

    int cqe = lane >> 4;
    __syncthreads();
    #pragma unroll
    for (int mi = 0; mi < 4; ++mi)
        #pragma unroll
        for (int ni = 0; ni < 4; ++ni){
            int lcol = wn + ni*16 + lr;
            bool colok = (col0 + lcol) < NP;
            #pragma unroll
            for (int v = 0; v < 4; ++v){
                int lrow = wm + mi*16 + cqe*4 + v;
                bool rowok = (row0 + lrow) < NP;
                ldsO[lrow*136 + lcol] = __float2half((colok && rowok) ? acc[mi][ni][v]*SCALE2INV : PADVAL);
            }
        }
    __syncthreads();
    {
        __half* tileD = P + (size_t)(b*4 + 0)*TSZ + ((size_t)bx*12 + by)*TILE;
        #pragma unroll
        for (int it = 0; it < 8; ++it){
            int e = it*256 + tid;
            int r = e >> 4, q = e & 15;
            *(uint4*)(tileD + r*128 + q*8) = *(const uint4*)(ldsO + r*136 + q*8);
        }
    }
}

// ---- persistent Sinkhorn: 4 OT groups x 16 blocks (fused colmin, v17 path) ----
__device__ __forceinline__ void groupbar(int* slot, int gsz){
    __syncthreads();
    if (threadIdx.x == 0){
        __hip_atomic_fetch_add(slot, 1, __ATOMIC_RELEASE, __HIP_MEMORY_SCOPE_AGENT);
        while (__hip_atomic_load(slot, __ATOMIC_ACQUIRE, __HIP_MEMORY_SCOPE_AGENT) < gsz)
            __builtin_amdgcn_s_sleep(1);
    }
    __syncthreads();
}

#define ROWPTR(PK, i) ((PK) + (size_t)((i) >> 7)*12*TILE + (size_t)((i) & 127)*128)

__global__ __launch_bounds__(1024, 1) void k_sink(const __half* __restrict__ P,
        float* __restrict__ fs, float* __restrict__ uvv,
        int* __restrict__ bars, int* __restrict__ flags,
        unsigned* __restrict__ cmin){
    int tid = threadIdx.x;
    int lane = tid & 63;
    int wid = tid >> 6;
    int blk = (int)blockIdx.x;
    __shared__ int s_ch;
    __shared__ unsigned lmin[1536];

    int b = blk / OTB, lb = blk - b*OTB;
    int gw = lb*16 + wid;
    const int NWV = OTB*16;     // 256 waves
    int* gbarp  = bars + b*64;
    int* gflagp = flags + b*64;
    const __half* P0 = P + (size_t)(b*4 + 0)*TSZ;
    float* fsb = fs + b*VSZ;
    float* uvb = uvv + b*VSZ;
    unsigned* cm = cmin + b*3*1536;

    int colb[3];
    #pragma unroll
    for (int it = 0; it < 3; ++it){
        int c = lane + it*64;
        colb[it] = ((c >> 4) << 7) + ((c & 15) << 3);
    }

    int lastT = 0;
    for (int t = 0; t < 30; ++t){
        unsigned* rdbuf = cm + ((t + 2) % 3)*1536;
        unsigned* wrbuf = cm + (t % 3)*1536;
        unsigned* rsbuf = cm + ((t + 1) % 3)*1536;
        if (tid == 0) s_ch = 0;
        for (int idx = tid; idx < 1536; idx += 1024) lmin[idx] = 0xFFFFFFFFu;
        float Au[3][8];
        #pragma unroll
        for (int it = 0; it < 3; ++it){
            uint4 k0 = *(const uint4*)(rdbuf + colb[it]);
            uint4 k1 = *(const uint4*)(rdbuf + colb[it] + 4);
            unsigned kk[8] = {k0.x, k0.y, k0.z, k0.w, k1.x, k1.y, k1.z, k1.w};
            #pragma unroll
            for (int e = 0; e < 8; ++e){
                int col = colb[it] + e;
                Au[it][e] = (col < NP) ? (-(funkey(kk[e]) + KADD)) : 3.0e38f;
            }
        }
        __syncthreads();
        float amin[3][8];
        #pragma unroll
        for (int it = 0; it < 3; ++it)
            #pragma unroll
            for (int e = 0; e < 8; ++e) amin[it][e] = 3.0e38f;
        int ch = 0;
        for (int i = gw; i < NP; i += NWV){
            const __half* rowb = ROWPTR(P0, i);
            uint4 pk[3];
            #pragma unroll
            for (int it = 0; it < 3; ++it){
                int c = lane + it*64, tt = c >> 4, q = c & 15;
                pk[it] = *(const uint4*)(rowb + (size_t)tt*TILE + q*8);
            }
            float cf[3][8];
            float m = 3.0e38f;
            #pragma unroll
            for (int it = 0; it < 3; ++it){
                float2 c0 = __half22float2(*(const __half2*)&pk[it].x);
                float2 c1 = __half22float2(*(const __half2*)&pk[it].y);
                float2 c2 = __half22float2(*(const __half2*)&pk[it].z);
                float2 c3 = __half22float2(*(const __half2*)&pk[it].w);
                cf[it][0] = c0.x; cf[it][1] = c0.y; cf[it][2] = c1.x; cf[it][3] = c1.y;
                cf[it][4] = c2.x; cf[it][5] = c2.y; cf[it][6] = c3.x; cf[it][7] = c3.y;
                #pragma unroll
                for (int e = 0; e < 8; ++e) m = fminf(m, Au[it][e] - cf[it][e]);
            }
            #pragma unroll
            for (int o = 1; o < 64; o <<= 1) m = fminf(m, __shfl_xor(m, o, 64));
            float nv = -(m + KADD);
            if (lane == 0){
                if (fabsf(nv - fsb[i]) > FTHR) ch = 1;
                fsb[i] = nv;
            }
            #pragma unroll
            for (int it = 0; it < 3; ++it)
                #pragma unroll
                for (int e = 0; e < 8; ++e)
                    amin[it][e] = fminf(amin[it][e], nv - cf[it][e]);
        }
        if (ch) s_ch = 1;
        #pragma unroll
        for (int it = 0; it < 3; ++it)
            #pragma unroll
            for (int e = 0; e < 8; ++e)
                atomicMin(&lmin[colb[it] + e], fkey(amin[it][e]));
        __syncthreads();
        for (int idx = tid; idx < 1536; idx += 1024)
            atomicMin(&wrbuf[idx], lmin[idx]);
        if (tid < 96) rsbuf[lb*96 + tid] = 0xFFFFFFFFu;
        if (tid == 0 && s_ch) atomicOr(&gflagp[t], 1);
        groupbar(&gbarp[t], OTB);
        lastT = t;
        int fA = __hip_atomic_load(&gflagp[t], __ATOMIC_RELAXED, __HIP_MEMORY_SCOPE_AGENT);
        if (fA == 0) break;
    }
    unsigned* fin = cm + (lastT % 3)*1536;
    for (int j = tid; j < NP; j += 1024)
        uvb[j] = -(funkey(fin[j]) + KADD);
}

// S = (4/1500) * sum_b,i (xnrm + ynrm - fs - u)   [self potentials ~ 0: dropped]
__global__ void k_final(const float* __restrict__ fs, const float* __restrict__ u,
                        const float* __restrict__ xnrm, const float* __restrict__ ynrm,
                        float* __restrict__ out){
    __shared__ double red[256];
    double s = 0.0;
    for (int t = threadIdx.x; t < NB*NP; t += 256){
        int b = t / NP, i = t - b*NP; int o = b*VSZ + i;
        s += (double)xnrm[o] + (double)ynrm[o] - (double)fs[o] - (double)u[o];
    }
    red[threadIdx.x] = s; __syncthreads();
    for (int w = 128; w > 0; w >>= 1){
        if (threadIdx.x < w) red[threadIdx.x] += red[threadIdx.x + w];
        __syncthreads();
    }
    if (threadIdx.x == 0) out[0] = (float)(red[0] * (4.0/1500.0));
}

extern "C" void kernel_launch(void* const* d_in, const int* in_sizes, int n_in,
                              void* d_out, int out_size, void* d_ws, size_t ws_size,
                              hipStream_t stream) {
    const float* x = (const float*)d_in[0];
    const float* y = (const float*)d_in[1];
    float* out = (float*)d_out;

    __half* pxh = (__half*)d_ws;
    __half* pyh = pxh + (size_t)NB*NP*DP;
    float* csx = (float*)(pyh + (size_t)NB*NP*DP);
    float* csy = csx + NB*DD;
    float* fs  = csy + NB*DD;
    float* uv  = fs + NB*VSZ;
    float* xnrm = uv + NB*VSZ;
    float* ynrm = xnrm + NB*VSZ;
    int* bars  = (int*)(ynrm + NB*VSZ);                // 12*64 ints
    int* flags = bars + 12*64;                         // 12*64 ints
    unsigned* cmin = (unsigned*)(flags + 12*64);       // 4*3*1536 uints
    float* partial = (float*)(cmin + 4*3*1536);        // 12*NB*2*DD floats
    float* smallEnd = partial + (size_t)12*NB*2*DD;
    size_t pOff = (((size_t)((char*)smallEnd - (char*)d_ws)) + 255) & ~(size_t)255;
    __half* P = (__half*)((char*)d_ws + pOff);

    int nzero = (int)(((float*)(flags + 12*64)) - csx);
    int nkeys = 4*3*1536;
    k_init<<<(nzero + nkeys + 255)/256, 256, 0, stream>>>(csx, nzero, cmin, nkeys);

    k_colsum_p1<<<dim3(12, NB, 2), 256, 0, stream>>>(x, y, partial);
    k_colsum_p2<<<10, 256, 0, stream>>>(partial, csx, csy);

    k_normrow<<<3000, 256, 0, stream>>>(x, y, csx, csy, pxh, pyh, xnrm, uv, ynrm, cmin);

    k_gemm_mfma<<<dim3(12, 12, NB), 256, 0, stream>>>(pxh, pyh, P);

    k_sink<<<4*OTB, 1024, 0, stream>>>(P, fs, uv, bars, flags, cmin);

    k_final<<<1, 256, 0, stream>>>(fs, uv, xnrm, ynrm, out);
}

// Round 24
// 114.206 us; speedup vs baseline: 1.7739x; 1.1788x over previous
//
// v19 — v18 with k_colsum_p1 parallelized: 125 chunks x 12 rows (1000 blocks, 12
// unrolled loads/thread) instead of 12 chunks x 125 rows (96 blocks, latency-bound
// at 127 GB/s). p2 sums 125 partials. Everything else identical to v18 (best: 134.6).
#include <hip/hip_runtime.h>
#include <hip/hip_fp16.h>

#define NP 1500
#define DD 300
#define DP 320
#define VSZ 1536
#define NB 4
#define TILE 16384
#define TSZ (1536*1536)
#define OTB 16              // blocks per OT group
#define NCH 125             // colsum chunks (12 rows each)
#define KADD 1.8283051e-8f
#define PADVAL (-60000.0f)
#define SCALE 256.0f
#define SCALE2INV (1.0f/65536.0f)
#define FTHR 1e-8f

typedef _Float16 f16x8 __attribute__((ext_vector_type(8)));
typedef float f32x4 __attribute__((ext_vector_type(4)));

__device__ __forceinline__ unsigned fkey(float f){
    unsigned b = __float_as_uint(f);
    return (b & 0x80000000u) ? ~b : (b | 0x80000000u);
}
__device__ __forceinline__ float funkey(unsigned k){
    unsigned b = (k & 0x80000000u) ? (k & 0x7FFFFFFFu) : ~k;
    return __uint_as_float(b);
}

// zero nz floats then set nk uints to 0xFFFFFFFF (one launch)
__global__ void k_init(float* pz, int nz, unsigned* pk, int nk){
    int i = blockIdx.x*blockDim.x + threadIdx.x;
    if (i < nz) pz[i] = 0.f;
    int j = i - nz;
    if (j >= 0 && j < nk) pk[j] = 0xFFFFFFFFu;
}

// ---- deterministic column sums: 125 chunks x 12 rows ----
__global__ __launch_bounds__(256) void k_colsum_p1(const float* __restrict__ x, const float* __restrict__ y,
                                                   float* __restrict__ partial){
    int rc = blockIdx.x, b = blockIdx.y, src = blockIdx.z;
    const float* in = (src ? y : x) + ((size_t)b*NP + rc*12)*DD;
    int tid = threadIdx.x;
    float s0 = 0.f, s1 = 0.f;
    #pragma unroll
    for (int r = 0; r < 12; ++r){
        float v0 = in[r*DD + tid];
        s0 = fmaf(v0, v0, s0);
        if (tid < 44){
            float v1 = in[r*DD + 256 + tid];
            s1 = fmaf(v1, v1, s1);
        }
    }
    float* po = partial + (((size_t)rc*NB + b)*2 + src)*DD;
    po[tid] = s0;
    if (tid < 44) po[256 + tid] = s1;
}

__global__ void k_colsum_p2(const float* __restrict__ partial,
                            float* __restrict__ csx, float* __restrict__ csy){
    int idx = blockIdx.x*256 + threadIdx.x;
    if (idx >= NB*2*DD) return;
    int c = idx % DD; int t = idx / DD; int src = t & 1; int b = t >> 1;
    float s = 0.f;
    for (int rc = 0; rc < NCH; ++rc)
        s += partial[(((size_t)rc*NB + b)*2 + src)*DD + c];
    (src ? csy : csx)[b*DD + c] = s;
}

// ---- normalize + row-norm init; side1 seeds OT cmin buffer 2 with fkey(-(ynrm+KADD)) ----
__global__ __launch_bounds__(256) void k_normrow(const float* __restrict__ x, const float* __restrict__ y,
        const float* __restrict__ csx, const float* __restrict__ csy,
        __half* __restrict__ pxh, __half* __restrict__ pyh,
        float* __restrict__ xnrm, float* __restrict__ uvv, float* __restrict__ ynrm,
        unsigned* __restrict__ cmin){
    int gw = ((int)blockIdx.x*256 + threadIdx.x) >> 6;
    int lane = threadIdx.x & 63;
    int src = (gw >= NB*NP) ? 1 : 0;
    int rem = gw - src*NB*NP;
    int b = rem / NP, i = rem - b*NP;
    const float* in = (src ? y : x) + ((size_t)b*NP + i)*DD;
    const float* cs = (src ? csy : csx) + b*DD;
    __half* oph = (src ? pyh : pxh) + ((size_t)b*NP + i)*DP;
    float s = 0.f;
    #pragma unroll
    for (int it = 0; it < 5; ++it){
        int c = lane + it*64;
        float vu = 0.f, hv = 0.f;
        if (c < DD){
            float u = in[c];
            vu = u*u / cs[c];
            hv = vu * SCALE;
        }
        oph[c] = __float2half(hv);
        s = fmaf(vu, vu, s);
    }
    #pragma unroll
    for (int o2 = 1; o2 < 64; o2 <<= 1) s += __shfl_xor(s, o2, 64);
    if (lane == 0){
        float val = 0.5f * s;
        int o = b*VSZ + i;
        if (src){
            uvv[o] = val; ynrm[o] = val;
            cmin[(b*3 + 2)*1536 + i] = fkey(-(val + KADD));
        } else {
            xnrm[o] = val;
        }
    }
}

// ---- MFMA GEMM: kind0 (Pxy) ONLY. BK=64, prefetch, swizzled LDS, plain stores ----
__global__ __launch_bounds__(256) void k_gemm_mfma(const __half* __restrict__ pxh,
                                                   const __half* __restrict__ pyh,
                                                   __half* __restrict__ P){
    int b = blockIdx.z;
    int bx = blockIdx.x, by = blockIdx.y;
    const __half* A = pxh + (size_t)b*NP*DP;
    const __half* B = pyh + (size_t)b*NP*DP;

    __shared__ __align__(16) char smem[128*136*2];
    char* ldsA = smem;
    char* ldsB = smem + 16384;
    __half* ldsO = (__half*)smem;

    int tid = threadIdx.x;
    int row0 = bx*128, col0 = by*128;
    int lane = tid & 63;
    int w = tid >> 6;
    int wm = (w >> 1)*64, wn = (w & 1)*64;
    int g8 = tid & 7, rw = tid >> 3;
    int lr = lane & 15, cq = lane >> 4;

    f32x4 acc[4][4];
    #pragma unroll
    for (int mi = 0; mi < 4; ++mi)
        #pragma unroll
        for (int ni = 0; ni < 4; ++ni)
            acc[mi][ni] = (f32x4){0.f, 0.f, 0.f, 0.f};

    uint4 va[4], vb[4];
    #pragma unroll
    for (int is = 0; is < 4; ++is){
        int r = rw + is*32;
        int ar = row0 + r; if (ar > NP-1) ar = NP-1;
        int br = col0 + r; if (br > NP-1) br = NP-1;
        va[is] = *(const uint4*)(A + (size_t)ar*DP + g8*8);
        vb[is] = *(const uint4*)(B + (size_t)br*DP + g8*8);
    }
    #pragma unroll
    for (int ks = 0; ks < 5; ++ks){
        if (ks) __syncthreads();
        #pragma unroll
        for (int is = 0; is < 4; ++is){
            int r = rw + is*32;
            int pc = g8 ^ (r & 7);
            *(uint4*)(ldsA + r*128 + pc*16) = va[is];
            *(uint4*)(ldsB + r*128 + pc*16) = vb[is];
        }
        __syncthreads();
        if (ks < 4){
            int k0 = (ks + 1)*64;
            #pragma unroll
            for (int is = 0; is < 4; ++is){
                int r = rw + is*32;
                int ar = row0 + r; if (ar > NP-1) ar = NP-1;
                int br = col0 + r; if (br > NP-1) br = NP-1;
                va[is] = *(const uint4*)(A + (size_t)ar*DP + k0 + g8*8);
                vb[is] = *(const uint4*)(B + (size_t)br*DP + k0 + g8*8);
            }
        }
        f16x8 av[2][4], bv[2][4];
        #pragma unroll
        for (int ksl = 0; ksl < 2; ++ksl){
            int lc = ksl*4 + cq;
            int pc = (lc ^ (lr & 7))*16;
            #pragma unroll
            for (int mi = 0; mi < 4; ++mi)
                av[ksl][mi] = *(const f16x8*)(ldsA + (wm + mi*16 + lr)*128 + pc);
            #pragma unroll
            for (int ni = 0; ni < 4; ++ni)
                bv[ksl][ni] = *(const f16x8*)(ldsB + (wn + ni*16 + lr)*128 + pc);
        }
        #pragma unroll
        for (int ksl = 0; ksl < 2; ++ksl)
            #pragma unroll
            for (int mi = 0; mi < 4; ++mi)
                #pragma unroll
                for (int ni = 0; ni < 4; ++ni)
                    acc[mi][ni] = __builtin_amdgcn_mfma_f32_16x16x32_f16(av[ksl][mi], bv[ksl][ni], acc[mi][ni], 0, 0, 0);
    }

    int cqe = lane >> 4;
    __syncthreads();
    #pragma unroll
    for (int mi = 0; mi < 4; ++mi)
        #pragma unroll
        for (int ni = 0; ni < 4; ++ni){
            int lcol = wn + ni*16 + lr;
            bool colok = (col0 + lcol) < NP;
            #pragma unroll
            for (int v = 0; v < 4; ++v){
                int lrow = wm + mi*16 + cqe*4 + v;
                bool rowok = (row0 + lrow) < NP;
                ldsO[lrow*136 + lcol] = __float2half((colok && rowok) ? acc[mi][ni][v]*SCALE2INV : PADVAL);
            }
        }
    __syncthreads();
    {
        __half* tileD = P + (size_t)(b*4 + 0)*TSZ + ((size_t)bx*12 + by)*TILE;
        #pragma unroll
        for (int it = 0; it < 8; ++it){
            int e = it*256 + tid;
            int r = e >> 4, q = e & 15;
            *(uint4*)(tileD + r*128 + q*8) = *(const uint4*)(ldsO + r*136 + q*8);
        }
    }
}

// ---- persistent Sinkhorn: 4 OT groups x 16 blocks (fused colmin) ----
__device__ __forceinline__ void groupbar(int* slot, int gsz){
    __syncthreads();
    if (threadIdx.x == 0){
        __hip_atomic_fetch_add(slot, 1, __ATOMIC_RELEASE, __HIP_MEMORY_SCOPE_AGENT);
        while (__hip_atomic_load(slot, __ATOMIC_ACQUIRE, __HIP_MEMORY_SCOPE_AGENT) < gsz)
            __builtin_amdgcn_s_sleep(1);
    }
    __syncthreads();
}

#define ROWPTR(PK, i) ((PK) + (size_t)((i) >> 7)*12*TILE + (size_t)((i) & 127)*128)

__global__ __launch_bounds__(1024, 1) void k_sink(const __half* __restrict__ P,
        float* __restrict__ fs, float* __restrict__ uvv,
        int* __restrict__ bars, int* __restrict__ flags,
        unsigned* __restrict__ cmin){
    int tid = threadIdx.x;
    int lane = tid & 63;
    int wid = tid >> 6;
    int blk = (int)blockIdx.x;
    __shared__ int s_ch;
    __shared__ unsigned lmin[1536];

    int b = blk / OTB, lb = blk - b*OTB;
    int gw = lb*16 + wid;
    const int NWV = OTB*16;     // 256 waves
    int* gbarp  = bars + b*64;
    int* gflagp = flags + b*64;
    const __half* P0 = P + (size_t)(b*4 + 0)*TSZ;
    float* fsb = fs + b*VSZ;
    float* uvb = uvv + b*VSZ;
    unsigned* cm = cmin + b*3*1536;

    int colb[3];
    #pragma unroll
    for (int it = 0; it < 3; ++it){
        int c = lane + it*64;
        colb[it] = ((c >> 4) << 7) + ((c & 15) << 3);
    }

    int lastT = 0;
    for (int t = 0; t < 30; ++t){
        unsigned* rdbuf = cm + ((t + 2) % 3)*1536;
        unsigned* wrbuf = cm + (t % 3)*1536;
        unsigned* rsbuf = cm + ((t + 1) % 3)*1536;
        if (tid == 0) s_ch = 0;
        for (int idx = tid; idx < 1536; idx += 1024) lmin[idx] = 0xFFFFFFFFu;
        float Au[3][8];
        #pragma unroll
        for (int it = 0; it < 3; ++it){
            uint4 k0 = *(const uint4*)(rdbuf + colb[it]);
            uint4 k1 = *(const uint4*)(rdbuf + colb[it] + 4);
            unsigned kk[8] = {k0.x, k0.y, k0.z, k0.w, k1.x, k1.y, k1.z, k1.w};
            #pragma unroll
            for (int e = 0; e < 8; ++e){
                int col = colb[it] + e;
                Au[it][e] = (col < NP) ? (-(funkey(kk[e]) + KADD)) : 3.0e38f;
            }
        }
        __syncthreads();
        float amin[3][8];
        #pragma unroll
        for (int it = 0; it < 3; ++it)
            #pragma unroll
            for (int e = 0; e < 8; ++e) amin[it][e] = 3.0e38f;
        int ch = 0;
        for (int i = gw; i < NP; i += NWV){
            const __half* rowb = ROWPTR(P0, i);
            uint4 pk[3];
            #pragma unroll
            for (int it = 0; it < 3; ++it){
                int c = lane + it*64, tt = c >> 4, q = c & 15;
                pk[it] = *(const uint4*)(rowb + (size_t)tt*TILE + q*8);
            }
            float cf[3][8];
            float m = 3.0e38f;
            #pragma unroll
            for (int it = 0; it < 3; ++it){
                float2 c0 = __half22float2(*(const __half2*)&pk[it].x);
                float2 c1 = __half22float2(*(const __half2*)&pk[it].y);
                float2 c2 = __half22float2(*(const __half2*)&pk[it].z);
                float2 c3 = __half22float2(*(const __half2*)&pk[it].w);
                cf[it][0] = c0.x; cf[it][1] = c0.y; cf[it][2] = c1.x; cf[it][3] = c1.y;
                cf[it][4] = c2.x; cf[it][5] = c2.y; cf[it][6] = c3.x; cf[it][7] = c3.y;
                #pragma unroll
                for (int e = 0; e < 8; ++e) m = fminf(m, Au[it][e] - cf[it][e]);
            }
            #pragma unroll
            for (int o = 1; o < 64; o <<= 1) m = fminf(m, __shfl_xor(m, o, 64));
            float nv = -(m + KADD);
            if (lane == 0){
                if (fabsf(nv - fsb[i]) > FTHR) ch = 1;
                fsb[i] = nv;
            }
            #pragma unroll
            for (int it = 0; it < 3; ++it)
                #pragma unroll
                for (int e = 0; e < 8; ++e)
                    amin[it][e] = fminf(amin[it][e], nv - cf[it][e]);
        }
        if (ch) s_ch = 1;
        #pragma unroll
        for (int it = 0; it < 3; ++it)
            #pragma unroll
            for (int e = 0; e < 8; ++e)
                atomicMin(&lmin[colb[it] + e], fkey(amin[it][e]));
        __syncthreads();
        for (int idx = tid; idx < 1536; idx += 1024)
            atomicMin(&wrbuf[idx], lmin[idx]);
        if (tid < 96) rsbuf[lb*96 + tid] = 0xFFFFFFFFu;
        if (tid == 0 && s_ch) atomicOr(&gflagp[t], 1);
        groupbar(&gbarp[t], OTB);
        lastT = t;
        int fA = __hip_atomic_load(&gflagp[t], __ATOMIC_RELAXED, __HIP_MEMORY_SCOPE_AGENT);
        if (fA == 0) break;
    }
    unsigned* fin = cm + (lastT % 3)*1536;
    for (int j = tid; j < NP; j += 1024)
        uvb[j] = -(funkey(fin[j]) + KADD);
}

// S = (4/1500) * sum_b,i (xnrm + ynrm - fs - u)
__global__ void k_final(const float* __restrict__ fs, const float* __restrict__ u,
                        const float* __restrict__ xnrm, const float* __restrict__ ynrm,
                        float* __restrict__ out){
    __shared__ double red[256];
    double s = 0.0;
    for (int t = threadIdx.x; t < NB*NP; t += 256){
        int b = t / NP, i = t - b*NP; int o = b*VSZ + i;
        s += (double)xnrm[o] + (double)ynrm[o] - (double)fs[o] - (double)u[o];
    }
    red[threadIdx.x] = s; __syncthreads();
    for (int w = 128; w > 0; w >>= 1){
        if (threadIdx.x < w) red[threadIdx.x] += red[threadIdx.x + w];
        __syncthreads();
    }
    if (threadIdx.x == 0) out[0] = (float)(red[0] * (4.0/1500.0));
}

extern "C" void kernel_launch(void* const* d_in, const int* in_sizes, int n_in,
                              void* d_out, int out_size, void* d_ws, size_t ws_size,
                              hipStream_t stream) {
    const float* x = (const float*)d_in[0];
    const float* y = (const float*)d_in[1];
    float* out = (float*)d_out;

    __half* pxh = (__half*)d_ws;
    __half* pyh = pxh + (size_t)NB*NP*DP;
    float* csx = (float*)(pyh + (size_t)NB*NP*DP);
    float* csy = csx + NB*DD;
    float* fs  = csy + NB*DD;
    float* uv  = fs + NB*VSZ;
    float* xnrm = uv + NB*VSZ;
    float* ynrm = xnrm + NB*VSZ;
    int* bars  = (int*)(ynrm + NB*VSZ);                // 12*64 ints
    int* flags = bars + 12*64;                         // 12*64 ints
    unsigned* cmin = (unsigned*)(flags + 12*64);       // 4*3*1536 uints
    float* partial = (float*)(cmin + 4*3*1536);        // NCH*NB*2*DD floats
    float* smallEnd = partial + (size_t)NCH*NB*2*DD;
    size_t pOff = (((size_t)((char*)smallEnd - (char*)d_ws)) + 255) & ~(size_t)255;
    __half* P = (__half*)((char*)d_ws + pOff);

    int nzero = (int)(((float*)(flags + 12*64)) - csx);
    int nkeys = 4*3*1536;
    k_init<<<(nzero + nkeys + 255)/256, 256, 0, stream>>>(csx, nzero, cmin, nkeys);

    k_colsum_p1<<<dim3(NCH, NB, 2), 256, 0, stream>>>(x, y, partial);
    k_colsum_p2<<<10, 256, 0, stream>>>(partial, csx, csy);

    k_normrow<<<3000, 256, 0, stream>>>(x, y, csx, csy, pxh, pyh, xnrm, uv, ynrm, cmin);

    k_gemm_mfma<<<dim3(12, 12, NB), 256, 0, stream>>>(pxh, pyh, P);

    k_sink<<<4*OTB, 1024, 0, stream>>>(P, fs, uv, bars, flags, cmin);

    k_final<<<1, 256, 0, stream>>>(fs, uv, xnrm, ynrm, out);
}